// Round 1
// baseline (28983.704 us; speedup 1.0000x reference)
//
#include <hip/hip_runtime.h>

#define INF 385
#define HD 128

// ---------------- degree counting ----------------
__global__ void count_kernel(const int* __restrict__ idx, float* __restrict__ deg, int nE) {
    int i = blockIdx.x * blockDim.x + threadIdx.x;
    int stride = gridDim.x * blockDim.x;
    for (; i < nE; i += stride) atomicAdd(&deg[idx[i]], 1.0f);
}

__global__ void rsqrt_kernel(float* __restrict__ deg, int n) {
    int i = blockIdx.x * blockDim.x + threadIdx.x;
    int stride = gridDim.x * blockDim.x;
    for (; i < n; i += stride) deg[i] = rsqrtf(fmaxf(deg[i], 1.0f));
}

// ---------------- fp32 tiled GEMM: C[M,Nc] = op(rowscale.A [M,K] @ B [K,Nc] + bias) ----------------
#define BM 64
#define BN 64
#define BK 16

__global__ __launch_bounds__(256) void gemm_bias_kernel(
    const float* __restrict__ A, const float* __restrict__ B,
    const float* __restrict__ bias, const float* __restrict__ rowscale,
    float* __restrict__ C, int M, int Nc, int K, int do_relu)
{
    __shared__ float As[BK][BM + 1];
    __shared__ float Bs[BK][BN + 1];
    int bm = blockIdx.x * BM;
    int bn = blockIdx.y * BN;
    int tid = threadIdx.x;
    int tx = tid % 16, ty = tid / 16;
    float acc[4][4] = {};

    for (int k0 = 0; k0 < K; k0 += BK) {
        // A tile: BM x BK (64x16 = 1024 elems / 256 thr = 4 each)
        #pragma unroll
        for (int j = 0; j < 4; ++j) {
            int idx = tid + 256 * j;
            int r = idx / BK, c = idx % BK;
            int gr = bm + r, gc = k0 + c;
            float v = 0.f;
            if (gr < M && gc < K) {
                v = A[(size_t)gr * K + gc];
                if (rowscale) v *= rowscale[gr];
            }
            As[c][r] = v;
        }
        // B tile: BK x BN (16x64)
        #pragma unroll
        for (int j = 0; j < 4; ++j) {
            int idx = tid + 256 * j;
            int r = idx / BN, c = idx % BN;
            int gr = k0 + r, gc = bn + c;
            float v = 0.f;
            if (gr < K && gc < Nc) v = B[(size_t)gr * Nc + gc];
            Bs[r][c] = v;
        }
        __syncthreads();
        #pragma unroll
        for (int kk = 0; kk < BK; ++kk) {
            float a[4], b[4];
            #pragma unroll
            for (int i = 0; i < 4; ++i) a[i] = As[kk][ty * 4 + i];
            #pragma unroll
            for (int i = 0; i < 4; ++i) b[i] = Bs[kk][tx * 4 + i];
            #pragma unroll
            for (int i = 0; i < 4; ++i)
                #pragma unroll
                for (int j2 = 0; j2 < 4; ++j2)
                    acc[i][j2] += a[i] * b[j2];
        }
        __syncthreads();
    }

    #pragma unroll
    for (int i = 0; i < 4; ++i) {
        int gr = bm + ty * 4 + i;
        if (gr >= M) continue;
        #pragma unroll
        for (int j2 = 0; j2 < 4; ++j2) {
            int gc = bn + tx * 4 + j2;
            if (gc >= Nc) continue;
            float v = acc[i][j2];
            if (bias) v += bias[gc];
            if (do_relu) v = fmaxf(v, 0.f);
            C[(size_t)gr * Nc + gc] = v;
        }
    }
}

// ---------------- edge scatter: acc[dst] += msg[src] * rsq_in[dst] ----------------
__global__ __launch_bounds__(256) void scatter_kernel(
    const float* __restrict__ msg, const int* __restrict__ src,
    const int* __restrict__ dst, const float* __restrict__ rsq_in,
    float* __restrict__ acc, int nE)
{
    int tid = blockIdx.x * blockDim.x + threadIdx.x;
    int nthr = gridDim.x * blockDim.x;
    int lane = tid & 31;             // 32 threads/edge, float4 each (128 floats)
    int e = tid >> 5;
    int estep = nthr >> 5;
    for (; e < nE; e += estep) {
        int s = src[e];
        int d = dst[e];
        float r = rsq_in[d];
        float4 v = reinterpret_cast<const float4*>(msg + (size_t)s * HD)[lane];
        float* o = acc + (size_t)d * HD + lane * 4;
        atomicAdd(o + 0, v.x * r);
        atomicAdd(o + 1, v.y * r);
        atomicAdd(o + 2, v.z * r);
        atomicAdd(o + 3, v.w * r);
    }
}

// ---------------- relu + bias (up to 2 biases, for dst-type 2) ----------------
__global__ void relu_bias_kernel(const float4* __restrict__ acc,
                                 const float* __restrict__ b0,
                                 const float* __restrict__ b1,
                                 float4* __restrict__ out, int n4)
{
    int i = blockIdx.x * blockDim.x + threadIdx.x;
    int stride = gridDim.x * blockDim.x;
    for (; i < n4; i += stride) {
        int h = (i * 4) & (HD - 1);
        float4 v = acc[i];
        v.x += b0[h]; v.y += b0[h + 1]; v.z += b0[h + 2]; v.w += b0[h + 3];
        if (b1) { v.x += b1[h]; v.y += b1[h + 1]; v.z += b1[h + 2]; v.w += b1[h + 3]; }
        v.x = fmaxf(v.x, 0.f); v.y = fmaxf(v.y, 0.f);
        v.z = fmaxf(v.z, 0.f); v.w = fmaxf(v.w, 0.f);
        out[i] = v;
    }
}

extern "C" void kernel_launch(void* const* d_in, const int* in_sizes, int n_in,
                              void* d_out, int out_size, void* d_ws, size_t ws_size,
                              hipStream_t stream)
{
    const float* feat[4] = {(const float*)d_in[0], (const float*)d_in[1],
                            (const float*)d_in[2], (const float*)d_in[3]};
    const int* src_all = (const int*)d_in[4];
    const int* dst_all = (const int*)d_in[5];
    const float* Wp  = (const float*)d_in[6];
    const float* bp  = (const float*)d_in[7];
    const float* Wc1 = (const float*)d_in[8];
    const float* bc1 = (const float*)d_in[9];
    const float* Wc2 = (const float*)d_in[10];
    const float* bc2 = (const float*)d_in[11];

    const int N = in_sizes[0] / INF;      // 50000
    const int E = in_sizes[4] / 5;        // 1,600,000

    // etypes: k -> (src_type, dst_type)
    const int st_[5] = {0, 1, 3, 0, 2};
    const int dt_[5] = {1, 3, 2, 2, 0};

    // workspace layout
    float* rsq_out = (float*)d_ws;                       // 5*N
    float* rsq_in  = rsq_out + 5 * (size_t)N;            // 5*N
    float* hbuf    = rsq_in  + 5 * (size_t)N;            // 4*N*HD
    float* msg     = hbuf + 4 * (size_t)N * HD;          // N*HD
    float* outbuf  = (float*)d_out;                      // 4*N*HD

    // ---- degrees -> rsqrt(clip(deg,1)) ----
    hipMemsetAsync(rsq_out, 0, 10 * (size_t)N * sizeof(float), stream);
    for (int k = 0; k < 5; ++k) {
        count_kernel<<<1024, 256, 0, stream>>>(src_all + (size_t)k * E, rsq_out + (size_t)k * N, E);
        count_kernel<<<1024, 256, 0, stream>>>(dst_all + (size_t)k * E, rsq_in  + (size_t)k * N, E);
    }
    rsqrt_kernel<<<(10 * N + 255) / 256, 256, 0, stream>>>(rsq_out, 10 * N);

    // ---- input projections: hbuf[t] = relu(feat[t] @ Wp[t] + bp[t]) ----
    dim3 gproj((N + BM - 1) / BM, HD / BN);
    for (int t = 0; t < 4; ++t) {
        gemm_bias_kernel<<<gproj, 256, 0, stream>>>(
            feat[t], Wp + (size_t)t * INF * HD, bp + (size_t)t * HD, nullptr,
            hbuf + (size_t)t * N * HD, N, HD, INF, 1);
    }

    // ---- 2 hetero conv layers ----
    for (int layer = 0; layer < 2; ++layer) {
        const float* Wc = layer ? Wc2 : Wc1;
        const float* bc = layer ? bc2 : bc1;
        const float* hin = layer ? outbuf : hbuf;
        float* acc = layer ? hbuf : outbuf;

        hipMemsetAsync(acc, 0, 4 * (size_t)N * HD * sizeof(float), stream);

        dim3 gconv((N + BM - 1) / BM, HD / BN);
        for (int k = 0; k < 5; ++k) {
            // msg = (hin[st] * rsq_out[k]) @ Wc[k]
            gemm_bias_kernel<<<gconv, 256, 0, stream>>>(
                hin + (size_t)st_[k] * N * HD, Wc + (size_t)k * HD * HD,
                nullptr, rsq_out + (size_t)k * N,
                msg, N, HD, HD, 0);
            // acc[dt] += msg[src] * rsq_in[dst]
            scatter_kernel<<<2048, 256, 0, stream>>>(
                msg, src_all + (size_t)k * E, dst_all + (size_t)k * E,
                rsq_in + (size_t)k * N, acc + (size_t)dt_[k] * N * HD, E);
        }

        // relu + bias per dst ntype; t0<-bc[4], t1<-bc[0], t2<-bc[2]+bc[3], t3<-bc[1]
        const float* rb0[4] = {bc + 4 * HD, bc + 0, bc + 2 * HD, bc + 1 * HD};
        const float* rb1[4] = {nullptr, nullptr, bc + 3 * HD, nullptr};
        int n4 = N * HD / 4;
        for (int t = 0; t < 4; ++t) {
            relu_bias_kernel<<<(n4 + 255) / 256, 256, 0, stream>>>(
                (const float4*)(acc + (size_t)t * N * HD), rb0[t], rb1[t],
                (float4*)(outbuf + (size_t)t * N * HD), n4);
        }
    }
}

// Round 2
// 4740.706 us; speedup vs baseline: 6.1138x; 6.1138x over previous
//
#include <hip/hip_runtime.h>

#define INF 385
#define HD 128

// ---------------- histograms ----------------
__global__ void countf_kernel(const int* __restrict__ idx, float* __restrict__ deg, int nE) {
    int i = blockIdx.x * blockDim.x + threadIdx.x;
    int stride = gridDim.x * blockDim.x;
    for (; i < nE; i += stride) atomicAdd(&deg[idx[i]], 1.0f);
}

__global__ void counti_kernel(const int* __restrict__ idx, int* __restrict__ cnt, int nE) {
    int i = blockIdx.x * blockDim.x + threadIdx.x;
    int stride = gridDim.x * blockDim.x;
    for (; i < nE; i += stride) atomicAdd(&cnt[idx[i]], 1);
}

__global__ void rsqrt_kernel(float* __restrict__ deg, int n) {
    int i = blockIdx.x * blockDim.x + threadIdx.x;
    int stride = gridDim.x * blockDim.x;
    for (; i < n; i += stride) deg[i] = rsqrtf(fmaxf(deg[i], 1.0f));
}

__global__ void rsqrt_int_kernel(const int* __restrict__ cnt, float* __restrict__ rsq, int n) {
    int i = blockIdx.x * blockDim.x + threadIdx.x;
    int stride = gridDim.x * blockDim.x;
    for (; i < n; i += stride) rsq[i] = rsqrtf((float)max(cnt[i], 1));
}

// ---------------- single-workgroup exclusive scan (n ~ 50k) ----------------
__global__ __launch_bounds__(1024) void scan_kernel(const int* __restrict__ cnt,
                                                    int* __restrict__ off, int n) {
    __shared__ int ssum[1024];
    int t = threadIdx.x;
    int chunk = (n + 1023) / 1024;
    int lo = t * chunk, hi = min(lo + chunk, n);
    int s = 0;
    for (int i = lo; i < hi; ++i) s += cnt[i];
    ssum[t] = s;
    __syncthreads();
    for (int d = 1; d < 1024; d <<= 1) {
        int v = (t >= d) ? ssum[t - d] : 0;
        __syncthreads();
        ssum[t] += v;
        __syncthreads();
    }
    int excl = (t == 0) ? 0 : ssum[t - 1];
    for (int i = lo; i < hi; ++i) { off[i] = excl; excl += cnt[i]; }
    if (t == 1023) off[n] = excl;
}

// ---------------- bucket permutation: sorted_src grouped by dst ----------------
__global__ void permute_kernel(const int* __restrict__ src, const int* __restrict__ dst,
                               const int* __restrict__ off, int* __restrict__ cursor,
                               int* __restrict__ sorted_src, int nE) {
    int i = blockIdx.x * blockDim.x + threadIdx.x;
    int stride = gridDim.x * blockDim.x;
    for (; i < nE; i += stride) {
        int d = dst[i];
        int pos = off[d] + atomicAdd(&cursor[d], 1);
        sorted_src[pos] = src[i];
    }
}

// ---------------- fp32 tiled GEMM: C = op(rowscale.A @ B + bias) ----------------
#define BM 64
#define BN 64
#define BK 16

__global__ __launch_bounds__(256) void gemm_bias_kernel(
    const float* __restrict__ A, const float* __restrict__ B,
    const float* __restrict__ bias, const float* __restrict__ rowscale,
    float* __restrict__ C, int M, int Nc, int K, int do_relu)
{
    __shared__ float As[BK][BM + 1];
    __shared__ float Bs[BK][BN + 1];
    int bm = blockIdx.x * BM;
    int bn = blockIdx.y * BN;
    int tid = threadIdx.x;
    int tx = tid % 16, ty = tid / 16;
    float acc[4][4] = {};

    for (int k0 = 0; k0 < K; k0 += BK) {
        #pragma unroll
        for (int j = 0; j < 4; ++j) {
            int idx = tid + 256 * j;
            int r = idx / BK, c = idx % BK;
            int gr = bm + r, gc = k0 + c;
            float v = 0.f;
            if (gr < M && gc < K) {
                v = A[(size_t)gr * K + gc];
                if (rowscale) v *= rowscale[gr];
            }
            As[c][r] = v;
        }
        #pragma unroll
        for (int j = 0; j < 4; ++j) {
            int idx = tid + 256 * j;
            int r = idx / BN, c = idx % BN;
            int gr = k0 + r, gc = bn + c;
            float v = 0.f;
            if (gr < K && gc < Nc) v = B[(size_t)gr * Nc + gc];
            Bs[r][c] = v;
        }
        __syncthreads();
        #pragma unroll
        for (int kk = 0; kk < BK; ++kk) {
            float a[4], b[4];
            #pragma unroll
            for (int i = 0; i < 4; ++i) a[i] = As[kk][ty * 4 + i];
            #pragma unroll
            for (int i = 0; i < 4; ++i) b[i] = Bs[kk][tx * 4 + i];
            #pragma unroll
            for (int i = 0; i < 4; ++i)
                #pragma unroll
                for (int j2 = 0; j2 < 4; ++j2)
                    acc[i][j2] += a[i] * b[j2];
        }
        __syncthreads();
    }

    #pragma unroll
    for (int i = 0; i < 4; ++i) {
        int gr = bm + ty * 4 + i;
        if (gr >= M) continue;
        #pragma unroll
        for (int j2 = 0; j2 < 4; ++j2) {
            int gc = bn + tx * 4 + j2;
            if (gc >= Nc) continue;
            float v = acc[i][j2];
            if (bias) v += bias[gc];
            if (do_relu) v = fmaxf(v, 0.f);
            C[(size_t)gr * Nc + gc] = v;
        }
    }
}

// ---------------- CSR aggregation: one wave per dst node, no atomics ----------------
__global__ __launch_bounds__(256) void gather_agg_kernel(
    const float* __restrict__ msg, const int* __restrict__ sorted_src,
    const int* __restrict__ off, const float* __restrict__ rsq_in,
    float* __restrict__ acc, int n, int accumulate)
{
    int node = blockIdx.x * 4 + (threadIdx.x >> 6);
    if (node >= n) return;
    int lane = threadIdx.x & 63;
    int beg = off[node], end = off[node + 1];
    const float2* m2 = (const float2*)msg;
    float2 s = {0.f, 0.f};
    for (int e = beg; e < end; ++e) {
        int srcn = sorted_src[e];
        float2 v = m2[(size_t)srcn * (HD / 2) + lane];
        s.x += v.x; s.y += v.y;
    }
    float r = rsq_in[node];
    float2* o = (float2*)acc + (size_t)node * (HD / 2) + lane;
    if (accumulate) {
        float2 old = *o;
        s.x = old.x + s.x * r; s.y = old.y + s.y * r;
    } else {
        s.x *= r; s.y *= r;
    }
    *o = s;
}

// ---------------- relu + bias (up to 2 biases, for dst-type 2) ----------------
__global__ void relu_bias_kernel(const float4* __restrict__ acc,
                                 const float* __restrict__ b0,
                                 const float* __restrict__ b1,
                                 float4* __restrict__ out, int n4)
{
    int i = blockIdx.x * blockDim.x + threadIdx.x;
    int stride = gridDim.x * blockDim.x;
    for (; i < n4; i += stride) {
        int h = (i * 4) & (HD - 1);
        float4 v = acc[i];
        v.x += b0[h]; v.y += b0[h + 1]; v.z += b0[h + 2]; v.w += b0[h + 3];
        if (b1) { v.x += b1[h]; v.y += b1[h + 1]; v.z += b1[h + 2]; v.w += b1[h + 3]; }
        v.x = fmaxf(v.x, 0.f); v.y = fmaxf(v.y, 0.f);
        v.z = fmaxf(v.z, 0.f); v.w = fmaxf(v.w, 0.f);
        out[i] = v;
    }
}

extern "C" void kernel_launch(void* const* d_in, const int* in_sizes, int n_in,
                              void* d_out, int out_size, void* d_ws, size_t ws_size,
                              hipStream_t stream)
{
    const float* feat[4] = {(const float*)d_in[0], (const float*)d_in[1],
                            (const float*)d_in[2], (const float*)d_in[3]};
    const int* src_all = (const int*)d_in[4];
    const int* dst_all = (const int*)d_in[5];
    const float* Wp  = (const float*)d_in[6];
    const float* bp  = (const float*)d_in[7];
    const float* Wc1 = (const float*)d_in[8];
    const float* bc1 = (const float*)d_in[9];
    const float* Wc2 = (const float*)d_in[10];
    const float* bc2 = (const float*)d_in[11];

    const int N = in_sizes[0] / INF;      // 50000
    const int E = in_sizes[4] / 5;        // 1,600,000

    // etypes: k -> (src_type, dst_type)
    const int st_[5] = {0, 1, 3, 0, 2};
    const int dt_[5] = {1, 3, 2, 2, 0};

    // ---- workspace layout ----
    char* w = (char*)d_ws;
    float* rsq_out   = (float*)w;                 w += 5 * (size_t)N * 4;   // zeroed
    int*   cnt_dst   = (int*)w;                   w += 5 * (size_t)N * 4;   // zeroed
    int*   cursor    = (int*)w;                   w += 5 * (size_t)N * 4;   // zeroed
    float* rsq_in    = (float*)w;                 w += 5 * (size_t)N * 4;
    int*   off       = (int*)w;                   w += 5 * (size_t)(N + 1) * 4;
    int*   sorted    = (int*)w;                   w += 5 * (size_t)E * 4;   // 32 MB
    float* hbuf      = (float*)w;                 w += 4 * (size_t)N * HD * 4; // 102.4 MB
    float* msg       = (float*)w;                 w += (size_t)N * HD * 4;  // 25.6 MB
    float* outbuf    = (float*)d_out;

    // ---- degrees + CSR build (once; reused by both layers) ----
    hipMemsetAsync(rsq_out, 0, 15 * (size_t)N * 4, stream);  // rsq_out + cnt_dst + cursor
    for (int k = 0; k < 5; ++k) {
        countf_kernel<<<1024, 256, 0, stream>>>(src_all + (size_t)k * E, rsq_out + (size_t)k * N, E);
        counti_kernel<<<1024, 256, 0, stream>>>(dst_all + (size_t)k * E, cnt_dst + (size_t)k * N, E);
    }
    rsqrt_kernel<<<(5 * N + 255) / 256, 256, 0, stream>>>(rsq_out, 5 * N);
    rsqrt_int_kernel<<<(5 * N + 255) / 256, 256, 0, stream>>>(cnt_dst, rsq_in, 5 * N);
    for (int k = 0; k < 5; ++k) {
        scan_kernel<<<1, 1024, 0, stream>>>(cnt_dst + (size_t)k * N, off + (size_t)k * (N + 1), N);
        permute_kernel<<<2048, 256, 0, stream>>>(
            src_all + (size_t)k * E, dst_all + (size_t)k * E,
            off + (size_t)k * (N + 1), cursor + (size_t)k * N,
            sorted + (size_t)k * E, E);
    }

    // ---- input projections: hbuf[t] = relu(feat[t] @ Wp[t] + bp[t]) ----
    dim3 gproj((N + BM - 1) / BM, HD / BN);
    for (int t = 0; t < 4; ++t) {
        gemm_bias_kernel<<<gproj, 256, 0, stream>>>(
            feat[t], Wp + (size_t)t * INF * HD, bp + (size_t)t * HD, nullptr,
            hbuf + (size_t)t * N * HD, N, HD, INF, 1);
    }

    // ---- 2 hetero conv layers ----
    for (int layer = 0; layer < 2; ++layer) {
        const float* Wc = layer ? Wc2 : Wc1;
        const float* bc = layer ? bc2 : bc1;
        const float* hin = layer ? outbuf : hbuf;
        float* acc = layer ? hbuf : outbuf;

        dim3 gconv((N + BM - 1) / BM, HD / BN);
        for (int k = 0; k < 5; ++k) {
            // msg = (hin[st] * rsq_out[k]) @ Wc[k]
            gemm_bias_kernel<<<gconv, 256, 0, stream>>>(
                hin + (size_t)st_[k] * N * HD, Wc + (size_t)k * HD * HD,
                nullptr, rsq_out + (size_t)k * N,
                msg, N, HD, HD, 0);
            // acc[dt] (=|+=) segment_sum(msg[sorted_src]) * rsq_in
            // etype order: k2 writes t2, k3 accumulates into t2; others write.
            gather_agg_kernel<<<(N + 3) / 4, 256, 0, stream>>>(
                msg, sorted + (size_t)k * E, off + (size_t)k * (N + 1),
                rsq_in + (size_t)k * N, acc + (size_t)dt_[k] * N * HD, N,
                (k == 3) ? 1 : 0);
        }

        // relu + bias per dst ntype; t0<-bc[4], t1<-bc[0], t2<-bc[2]+bc[3], t3<-bc[1]
        const float* rb0[4] = {bc + 4 * HD, bc + 0, bc + 2 * HD, bc + 1 * HD};
        const float* rb1[4] = {nullptr, nullptr, bc + 3 * HD, nullptr};
        int n4 = N * HD / 4;
        for (int t = 0; t < 4; ++t) {
            relu_bias_kernel<<<(n4 + 255) / 256, 256, 0, stream>>>(
                (const float4*)(acc + (size_t)t * N * HD), rb0[t], rb1[t],
                (float4*)(outbuf + (size_t)t * N * HD), n4);
        }
    }
}

// Round 4
// 2491.855 us; speedup vs baseline: 11.6314x; 1.9025x over previous
//
#include <hip/hip_runtime.h>
#include <hip/hip_bf16.h>

#define INF 385
#define HD 128

typedef __attribute__((ext_vector_type(8))) short short8;
typedef __attribute__((ext_vector_type(4))) float f32x4;

__device__ inline unsigned short f2b(float f) {
    __hip_bfloat16 h = __float2bfloat16(f);
    return *reinterpret_cast<unsigned short*>(&h);
}
__device__ inline float b2f(unsigned int lo16) {
    union { unsigned int u; float f; } c; c.u = lo16 << 16; return c.f;
}

// ---------------- CSR build ----------------
__global__ void count_all_kernel(const int* __restrict__ src, const int* __restrict__ dst,
                                 int* __restrict__ cnt_src, int* __restrict__ cnt_dst,
                                 int E, int N) {
    int i = blockIdx.x * blockDim.x + threadIdx.x;
    int stride = gridDim.x * blockDim.x;
    int tot = 5 * E;
    for (; i < tot; i += stride) {
        int k = i / E;
        atomicAdd(&cnt_src[k * N + src[i]], 1);
        atomicAdd(&cnt_dst[k * N + dst[i]], 1);
    }
}

__global__ void rsq_kernel(const int* __restrict__ cs, const int* __restrict__ cd,
                           float* __restrict__ rsq_out, float* __restrict__ rsq_in, int n) {
    int i = blockIdx.x * blockDim.x + threadIdx.x;
    int stride = gridDim.x * blockDim.x;
    for (; i < n; i += stride) {
        rsq_out[i] = rsqrtf((float)max(cs[i], 1));
        rsq_in[i]  = rsqrtf((float)max(cd[i], 1));
    }
}

// 5 blocks, one per etype
__global__ __launch_bounds__(1024) void scan_kernel(const int* __restrict__ cnt_all,
                                                    int* __restrict__ off_all, int n) {
    const int* cnt = cnt_all + (size_t)blockIdx.x * n;
    int* off = off_all + (size_t)blockIdx.x * (n + 1);
    __shared__ int ssum[1024];
    int t = threadIdx.x;
    int chunk = (n + 1023) / 1024;
    int lo = t * chunk, hi = min(lo + chunk, n);
    int s = 0;
    for (int i = lo; i < hi; ++i) s += cnt[i];
    ssum[t] = s;
    __syncthreads();
    for (int d = 1; d < 1024; d <<= 1) {
        int v = (t >= d) ? ssum[t - d] : 0;
        __syncthreads();
        ssum[t] += v;
        __syncthreads();
    }
    int excl = (t == 0) ? 0 : ssum[t - 1];
    for (int i = lo; i < hi; ++i) { off[i] = excl; excl += cnt[i]; }
    if (t == 1023) off[n] = ssum[1023];
}

__global__ void permute_kernel(const int* __restrict__ src, const int* __restrict__ dst,
                               const int* __restrict__ off, int* __restrict__ cursor,
                               int* __restrict__ sorted_src, int E, int N) {
    int i = blockIdx.x * blockDim.x + threadIdx.x;
    int stride = gridDim.x * blockDim.x;
    int tot = 5 * E;
    for (; i < tot; i += stride) {
        int k = i / E;
        int d = dst[i];
        int pos = off[(size_t)k * (N + 1) + d] + atomicAdd(&cursor[(size_t)k * N + d], 1);
        sorted_src[(size_t)k * E + pos] = src[i];
    }
}

// ---------------- weight prep: transpose + bf16, combined biases ----------------
__global__ void prep_weights_kernel(const float* __restrict__ Wp,
                                    const float* __restrict__ Wc1, const float* __restrict__ Wc2,
                                    const float* __restrict__ bc1, const float* __restrict__ bc2,
                                    unsigned short* __restrict__ WpT,
                                    unsigned short* __restrict__ WcT,
                                    float* __restrict__ cbias) {
    int i = blockIdx.x * blockDim.x + threadIdx.x;
    int stride = gridDim.x * blockDim.x;
    const int nWp = 4 * 128 * 384;
    for (int p = i; p < nWp; p += stride) {
        int t = p / (128 * 384), rem = p % (128 * 384);
        int c = rem / 384, k = rem % 384;
        WpT[p] = f2b(Wp[(size_t)t * INF * HD + (size_t)k * HD + c]);
    }
    const int nWc = 5 * 128 * 128;
    for (int p = i; p < 2 * nWc; p += stride) {
        int layer = p / nWc, rem = p % nWc;
        int e = rem / (128 * 128), rem2 = rem % (128 * 128);
        int c = rem2 / 128, k = rem2 % 128;
        const float* W = layer ? Wc2 : Wc1;
        WcT[p] = f2b(W[(size_t)e * 128 * 128 + (size_t)k * 128 + c]);
    }
    // cbias[layer][t][c]: t0<-bc[4], t1<-bc[0], t2<-bc[2]+bc[3], t3<-bc[1]
    for (int p = i; p < 2 * 4 * 128; p += stride) {
        int layer = p / 512, rem = p % 512;
        int t = rem / 128, c = rem % 128;
        const float* bc = layer ? bc2 : bc1;
        float v;
        if (t == 0) v = bc[4 * 128 + c];
        else if (t == 1) v = bc[0 * 128 + c];
        else if (t == 2) v = bc[2 * 128 + c] + bc[3 * 128 + c];
        else v = bc[1 * 128 + c];
        cbias[p] = v;
    }
}

// ---------------- MFMA GEMM: out_bf16[M][128] = op( (A @ B) [*rowscale] [+rank1] [+bias] ) ----------------
// A: [M][lda] (f32 or bf16). Bt: [128][K] bf16 (pre-transposed weights).
// K must be a multiple of 64. Optional rank-1: + A[:,K] * wlast[col] (f32 path only).
template<int A_IS_F32>
__global__ __launch_bounds__(256) void gemm_mfma_kernel(
    const void* __restrict__ Araw, int lda,
    const unsigned short* __restrict__ Bt,
    const float* __restrict__ bias,
    const float* __restrict__ rowscale,
    const float* __restrict__ wlast,
    unsigned short* __restrict__ out,
    int M, int K, int relu)
{
    __shared__ __align__(16) unsigned short As[64][72];   // +8 pad: 144B row stride
    __shared__ __align__(16) unsigned short Bs[128][72];
    const int tid = threadIdx.x;
    const int bm = blockIdx.x * 64;
    const int wid = tid >> 6, lane = tid & 63;
    const int wr = wid & 1, wc = wid >> 1;      // 2x2 wave grid: 32 rows x 64 cols each
    const int l15 = lane & 15, l4 = lane >> 4;

    f32x4 acc[2][4] = {};

    for (int k0 = 0; k0 < K; k0 += 64) {
        if (A_IS_F32) {
            const float* A = (const float*)Araw;
            // 64x64 tile = 4096 elems, 16 per thread, coalesced in c
            #pragma unroll
            for (int j = 0; j < 16; ++j) {
                int p = tid + j * 256;
                int r = p >> 6, c = p & 63;
                int gm = bm + r;
                float v = (gm < M) ? A[(size_t)gm * lda + k0 + c] : 0.f;
                As[r][c] = f2b(v);
            }
        } else {
            const unsigned short* A = (const unsigned short*)Araw;
            int r = tid >> 2, q = tid & 3;      // 16 bf16 per thread, vectorized
            int gm = bm + r;
            if (gm < M) {
                const uint4* g = (const uint4*)(A + (size_t)gm * lda + k0 + q * 16);
                *(uint4*)&As[r][q * 16] = g[0];
                *(uint4*)&As[r][q * 16 + 8] = g[1];
            } else {
                uint4 z = {0, 0, 0, 0};
                *(uint4*)&As[r][q * 16] = z;
                *(uint4*)&As[r][q * 16 + 8] = z;
            }
        }
        {
            int col = tid >> 1, hf = tid & 1;   // 32 bf16 per thread from Bt[col][k0+hf*32..]
            const uint4* g = (const uint4*)(Bt + (size_t)col * K + k0 + hf * 32);
            #pragma unroll
            for (int j = 0; j < 4; ++j)
                *(uint4*)&Bs[col][hf * 32 + j * 8] = g[j];
        }
        __syncthreads();
        #pragma unroll
        for (int kk = 0; kk < 2; ++kk) {
            short8 a[2], b[4];
            #pragma unroll
            for (int mi = 0; mi < 2; ++mi)
                a[mi] = *(const short8*)&As[wr * 32 + mi * 16 + l15][kk * 32 + l4 * 8];
            #pragma unroll
            for (int ni = 0; ni < 4; ++ni)
                b[ni] = *(const short8*)&Bs[wc * 64 + ni * 16 + l15][kk * 32 + l4 * 8];
            #pragma unroll
            for (int mi = 0; mi < 2; ++mi)
                #pragma unroll
                for (int ni = 0; ni < 4; ++ni)
                    acc[mi][ni] = __builtin_amdgcn_mfma_f32_16x16x32_bf16(
                        a[mi], b[ni], acc[mi][ni], 0, 0, 0);
        }
        __syncthreads();
    }

    // epilogue: C/D layout col=lane&15, row=(lane>>4)*4+reg  [m89-verified]
    #pragma unroll
    for (int mi = 0; mi < 2; ++mi) {
        #pragma unroll
        for (int r = 0; r < 4; ++r) {
            int grow = bm + wr * 32 + mi * 16 + l4 * 4 + r;
            if (grow >= M) continue;
            float rs = rowscale ? rowscale[grow] : 1.f;
            float al = 0.f;
            if (wlast && A_IS_F32) al = ((const float*)Araw)[(size_t)grow * lda + K];
            #pragma unroll
            for (int ni = 0; ni < 4; ++ni) {
                int gcol = wc * 64 + ni * 16 + l15;
                float v = acc[mi][ni][r];
                if (wlast) v += al * wlast[gcol];
                if (bias) v += bias[gcol];
                v *= rs;
                if (relu) v = fmaxf(v, 0.f);
                out[(size_t)grow * HD + gcol] = f2b(v);
            }
        }
    }
}

// ---------------- CSR gather: one wave per node, fp32 accum, fused bias+relu ----------------
template<int DUAL, int OUT_BF16>
__global__ __launch_bounds__(256) void gather_kernel(
    const unsigned short* __restrict__ msgA, const int* __restrict__ sortedA,
    const int* __restrict__ offA, const float* __restrict__ rsqA,
    const unsigned short* __restrict__ msgB, const int* __restrict__ sortedB,
    const int* __restrict__ offB, const float* __restrict__ rsqB,
    const float* __restrict__ bias, void* __restrict__ outv, int n)
{
    int node = blockIdx.x * 4 + (threadIdx.x >> 6);
    if (node >= n) return;
    int lane = threadIdx.x & 63;

    float ox, oy;
    {
        float ax = 0.f, ay = 0.f;
        int beg = offA[node], end = offA[node + 1];
        int e = beg;
        for (; e + 1 < end; e += 2) {
            int s0 = sortedA[e], s1 = sortedA[e + 1];
            unsigned int v0 = *(const unsigned int*)(msgA + (size_t)s0 * HD + lane * 2);
            unsigned int v1 = *(const unsigned int*)(msgA + (size_t)s1 * HD + lane * 2);
            ax += b2f(v0 & 0xffffu) + b2f(v1 & 0xffffu);
            ay += b2f(v0 >> 16) + b2f(v1 >> 16);
        }
        if (e < end) {
            int s0 = sortedA[e];
            unsigned int v0 = *(const unsigned int*)(msgA + (size_t)s0 * HD + lane * 2);
            ax += b2f(v0 & 0xffffu);
            ay += b2f(v0 >> 16);
        }
        float r = rsqA[node];
        ox = ax * r; oy = ay * r;
    }
    if (DUAL) {
        float bx = 0.f, by = 0.f;
        int beg = offB[node], end = offB[node + 1];
        int e = beg;
        for (; e + 1 < end; e += 2) {
            int s0 = sortedB[e], s1 = sortedB[e + 1];
            unsigned int v0 = *(const unsigned int*)(msgB + (size_t)s0 * HD + lane * 2);
            unsigned int v1 = *(const unsigned int*)(msgB + (size_t)s1 * HD + lane * 2);
            bx += b2f(v0 & 0xffffu) + b2f(v1 & 0xffffu);
            by += b2f(v0 >> 16) + b2f(v1 >> 16);
        }
        if (e < end) {
            int s0 = sortedB[e];
            unsigned int v0 = *(const unsigned int*)(msgB + (size_t)s0 * HD + lane * 2);
            bx += b2f(v0 & 0xffffu);
            by += b2f(v0 >> 16);
        }
        float r = rsqB[node];
        ox += bx * r; oy += by * r;
    }
    float2 bv = *(const float2*)(bias + lane * 2);
    ox = fmaxf(ox + bv.x, 0.f);
    oy = fmaxf(oy + bv.y, 0.f);
    if (OUT_BF16) {
        unsigned int packed = ((unsigned int)f2b(oy) << 16) | f2b(ox);
        ((unsigned int*)outv)[(size_t)node * (HD / 2) + lane] = packed;
    } else {
        float2 o = {ox, oy};
        ((float2*)outv)[(size_t)node * (HD / 2) + lane] = o;
    }
}

extern "C" void kernel_launch(void* const* d_in, const int* in_sizes, int n_in,
                              void* d_out, int out_size, void* d_ws, size_t ws_size,
                              hipStream_t stream)
{
    const float* feat[4] = {(const float*)d_in[0], (const float*)d_in[1],
                            (const float*)d_in[2], (const float*)d_in[3]};
    const int* src_all = (const int*)d_in[4];
    const int* dst_all = (const int*)d_in[5];
    const float* Wp  = (const float*)d_in[6];
    const float* bp  = (const float*)d_in[7];
    const float* Wc1 = (const float*)d_in[8];
    const float* bc1 = (const float*)d_in[9];
    const float* Wc2 = (const float*)d_in[10];
    const float* bc2 = (const float*)d_in[11];

    const int N = in_sizes[0] / INF;      // 50000
    const int E = in_sizes[4] / 5;        // 1,600,000

    // etypes: k -> (src_type, dst_type): (0,1) (1,3) (3,2) (0,2) (2,0)
    const int st_[5] = {0, 1, 3, 0, 2};

    // ---- workspace layout (all offsets 256B-aligned) ----
    char* w = (char*)d_ws;
    auto take = [&](size_t bytes) { char* p = w; w += (bytes + 255) & ~(size_t)255; return p; };
    int*   cnt_src = (int*)take(5 * (size_t)N * 4);
    int*   cnt_dst = (int*)take(5 * (size_t)N * 4);
    int*   cursor  = (int*)take(5 * (size_t)N * 4);
    float* rsq_out = (float*)take(5 * (size_t)N * 4);
    float* rsq_in  = (float*)take(5 * (size_t)N * 4);
    int*   off     = (int*)take(5 * (size_t)(N + 1) * 4);
    int*   sorted  = (int*)take(5 * (size_t)E * 4);
    unsigned short* WpT = (unsigned short*)take(4 * 128 * 384 * 2);
    unsigned short* WcT = (unsigned short*)take(2 * 5 * 128 * 128 * 2);
    float* cbias   = (float*)take(2 * 4 * 128 * 4);
    unsigned short* h1   = (unsigned short*)take(4 * (size_t)N * HD * 2);
    unsigned short* msg0 = (unsigned short*)take((size_t)N * HD * 2);
    unsigned short* msg1 = (unsigned short*)take((size_t)N * HD * 2);
    unsigned short* h0 = (unsigned short*)d_out;   // dead before layer-2 output writes

    // ---- prep: weights + CSR ----
    hipMemsetAsync(cnt_src, 0, 3 * ((5 * (size_t)N * 4 + 255) & ~(size_t)255), stream);
    prep_weights_kernel<<<512, 256, 0, stream>>>(Wp, Wc1, Wc2, bc1, bc2, WpT, WcT, cbias);
    count_all_kernel<<<2048, 256, 0, stream>>>(src_all, dst_all, cnt_src, cnt_dst, E, N);
    rsq_kernel<<<(5 * N + 255) / 256, 256, 0, stream>>>(cnt_src, cnt_dst, rsq_out, rsq_in, 5 * N);
    scan_kernel<<<5, 1024, 0, stream>>>(cnt_dst, off, N);
    permute_kernel<<<2048, 256, 0, stream>>>(src_all, dst_all, off, cursor, sorted, E, N);

    const int gblk = (N + 63) / 64;

    // ---- input projections: h0[t] = relu(feat[t](f32) @ WpT[t] + rank1 + bp[t]) ----
    for (int t = 0; t < 4; ++t) {
        gemm_mfma_kernel<1><<<gblk, 256, 0, stream>>>(
            feat[t], INF, WpT + (size_t)t * 128 * 384,
            bp + (size_t)t * HD, nullptr,
            Wp + (size_t)t * INF * HD + 384 * HD,   // wlast = Wp[t][384][:]
            h0 + (size_t)t * N * HD, N, 384, 1);
    }

    // ---- 2 hetero conv layers ----
    for (int layer = 0; layer < 2; ++layer) {
        const unsigned short* hin = layer ? h1 : h0;
        const unsigned short* WT = WcT + (size_t)layer * 5 * 128 * 128;
        const float* cb = cbias + (size_t)layer * 4 * 128;
        void* outp = layer ? (void*)d_out : (void*)h1;
        const int OUTB = layer ? 0 : 1;

        auto conv_gemm = [&](int k, unsigned short* m) {
            gemm_mfma_kernel<0><<<gblk, 256, 0, stream>>>(
                hin + (size_t)st_[k] * N * HD, HD, WT + (size_t)k * 128 * 128,
                nullptr, rsq_out + (size_t)k * N, nullptr, m, N, 128, 0);
        };
        auto out_t = [&](int t) -> void* {
            return (char*)outp + (size_t)t * N * HD * (OUTB ? 2 : 4);
        };
        const int gg = (N + 3) / 4;

        // k=0: t0 -> t1
        conv_gemm(0, msg0);
        if (OUTB) gather_kernel<0, 1><<<gg, 256, 0, stream>>>(
            msg0, sorted + 0 * (size_t)E, off + 0 * (size_t)(N + 1), rsq_in + 0 * (size_t)N,
            nullptr, nullptr, nullptr, nullptr, cb + 1 * HD, out_t(1), N);
        else gather_kernel<0, 0><<<gg, 256, 0, stream>>>(
            msg0, sorted + 0 * (size_t)E, off + 0 * (size_t)(N + 1), rsq_in + 0 * (size_t)N,
            nullptr, nullptr, nullptr, nullptr, cb + 1 * HD, out_t(1), N);

        // k=1: t1 -> t3
        conv_gemm(1, msg0);
        if (OUTB) gather_kernel<0, 1><<<gg, 256, 0, stream>>>(
            msg0, sorted + 1 * (size_t)E, off + 1 * (size_t)(N + 1), rsq_in + 1 * (size_t)N,
            nullptr, nullptr, nullptr, nullptr, cb + 3 * HD, out_t(3), N);
        else gather_kernel<0, 0><<<gg, 256, 0, stream>>>(
            msg0, sorted + 1 * (size_t)E, off + 1 * (size_t)(N + 1), rsq_in + 1 * (size_t)N,
            nullptr, nullptr, nullptr, nullptr, cb + 3 * HD, out_t(3), N);

        // k=2 (t3->t2) + k=3 (t0->t2): dual gather
        conv_gemm(2, msg0);
        conv_gemm(3, msg1);
        if (OUTB) gather_kernel<1, 1><<<gg, 256, 0, stream>>>(
            msg0, sorted + 2 * (size_t)E, off + 2 * (size_t)(N + 1), rsq_in + 2 * (size_t)N,
            msg1, sorted + 3 * (size_t)E, off + 3 * (size_t)(N + 1), rsq_in + 3 * (size_t)N,
            cb + 2 * HD, out_t(2), N);
        else gather_kernel<1, 0><<<gg, 256, 0, stream>>>(
            msg0, sorted + 2 * (size_t)E, off + 2 * (size_t)(N + 1), rsq_in + 2 * (size_t)N,
            msg1, sorted + 3 * (size_t)E, off + 3 * (size_t)(N + 1), rsq_in + 3 * (size_t)N,
            cb + 2 * HD, out_t(2), N);

        // k=4: t2 -> t0
        conv_gemm(4, msg0);
        if (OUTB) gather_kernel<0, 1><<<gg, 256, 0, stream>>>(
            msg0, sorted + 4 * (size_t)E, off + 4 * (size_t)(N + 1), rsq_in + 4 * (size_t)N,
            nullptr, nullptr, nullptr, nullptr, cb + 0 * HD, out_t(0), N);
        else gather_kernel<0, 0><<<gg, 256, 0, stream>>>(
            msg0, sorted + 4 * (size_t)E, off + 4 * (size_t)(N + 1), rsq_in + 4 * (size_t)N,
            nullptr, nullptr, nullptr, nullptr, cb + 0 * HD, out_t(0), N);
    }
}

// Round 5
// 1686.618 us; speedup vs baseline: 17.1845x; 1.4774x over previous
//
#include <hip/hip_runtime.h>
#include <hip/hip_bf16.h>

#define INF 385
#define HD 128
#define NWG 8   // workgroups per histogram group

typedef __attribute__((ext_vector_type(8))) short short8;
typedef __attribute__((ext_vector_type(4))) float f32x4;

__device__ inline unsigned short f2b(float f) {
    __hip_bfloat16 h = __float2bfloat16(f);
    return *reinterpret_cast<unsigned short*>(&h);
}
__device__ inline float b2f(unsigned int lo16) {
    union { unsigned int u; float f; } c; c.u = lo16 << 16; return c.f;
}

// ---------------- LDS-privatized histogram + in-chunk ranks (no device atomics) ----------------
// grid = 10 groups * NWG; group g<5: dst side of etype g (writes rank_local);
// g>=5: src side of etype g-5.
__global__ __launch_bounds__(1024) void hist_kernel(
    const int* __restrict__ src_all, const int* __restrict__ dst_all,
    int* __restrict__ partial,               // [10][NWG][N]
    unsigned short* __restrict__ rank_local, // [5][E]
    int E, int N)
{
    __shared__ unsigned int cnt[25000];      // 2 packed ushort counters per uint
    int g = blockIdx.x / NWG;
    int w = blockIdx.x % NWG;
    int tid = threadIdx.x;
    int half = (N + 1) / 2;
    for (int i = tid; i < half; i += 1024) cnt[i] = 0;
    __syncthreads();

    int C = (E + NWG - 1) / NWG;
    int lo = w * C, hi = min(lo + C, E);
    if (g < 5) {
        const int* arr = dst_all + (size_t)g * E;
        for (int e = lo + tid; e < hi; e += 1024) {
            int d = arr[e];
            unsigned int sh = (d & 1) * 16;
            unsigned int old = atomicAdd(&cnt[d >> 1], 1u << sh);
            rank_local[(size_t)g * E + e] = (unsigned short)((old >> sh) & 0xffffu);
        }
    } else {
        const int* arr = src_all + (size_t)(g - 5) * E;
        for (int e = lo + tid; e < hi; e += 1024) {
            int d = arr[e];
            atomicAdd(&cnt[d >> 1], 1u << ((d & 1) * 16));
        }
    }
    __syncthreads();
    int* outp = partial + ((size_t)g * NWG + w) * N;
    for (int n = tid; n < N; n += 1024)
        outp[n] = (cnt[n >> 1] >> ((n & 1) * 16)) & 0xffffu;
}

// ---------------- reduce partials -> degrees/rsqrt; in-place exclusive prefix over chunks ----------------
__global__ void reduce_kernel(int* __restrict__ partial, int* __restrict__ cnt_dst,
                              float* __restrict__ rsq_out, float* __restrict__ rsq_in, int N) {
    int i = blockIdx.x * blockDim.x + threadIdx.x;
    int stride = gridDim.x * blockDim.x;
    int tot = 10 * N;
    for (; i < tot; i += stride) {
        int g = i / N, n = i - g * N;
        int* p = partial + ((size_t)g * NWG) * N + n;
        int sum = 0;
        #pragma unroll
        for (int w = 0; w < NWG; ++w) {
            int v = p[(size_t)w * N];
            p[(size_t)w * N] = sum;   // exclusive prefix (rank base per chunk)
            sum += v;
        }
        float r = rsqrtf((float)max(sum, 1));
        if (g < 5) { cnt_dst[i] = sum; rsq_in[i] = r; }
        else rsq_out[i - 5 * N] = r;
    }
}

// 5 blocks, one per etype
__global__ __launch_bounds__(1024) void scan_kernel(const int* __restrict__ cnt_all,
                                                    int* __restrict__ off_all, int n) {
    const int* cnt = cnt_all + (size_t)blockIdx.x * n;
    int* off = off_all + (size_t)blockIdx.x * (n + 1);
    __shared__ int ssum[1024];
    int t = threadIdx.x;
    int chunk = (n + 1023) / 1024;
    int lo = t * chunk, hi = min(lo + chunk, n);
    int s = 0;
    for (int i = lo; i < hi; ++i) s += cnt[i];
    ssum[t] = s;
    __syncthreads();
    for (int d = 1; d < 1024; d <<= 1) {
        int v = (t >= d) ? ssum[t - d] : 0;
        __syncthreads();
        ssum[t] += v;
        __syncthreads();
    }
    int excl = (t == 0) ? 0 : ssum[t - 1];
    for (int i = lo; i < hi; ++i) { off[i] = excl; excl += cnt[i]; }
    if (t == 1023) off[n] = ssum[1023];
}

// ---------------- atomic-free permutation: sorted_src grouped by dst ----------------
__global__ void permute_kernel(const int* __restrict__ src_all, const int* __restrict__ dst_all,
                               const int* __restrict__ off, const int* __restrict__ partial,
                               const unsigned short* __restrict__ rank_local,
                               int* __restrict__ sorted, int E, int N) {
    int i = blockIdx.x * blockDim.x + threadIdx.x;
    int stride = gridDim.x * blockDim.x;
    int tot = 5 * E;
    int C = (E + NWG - 1) / NWG;
    for (; i < tot; i += stride) {
        int k = i / E, e = i - k * E;
        int w = e / C;
        int d = dst_all[i];
        int pos = off[(size_t)k * (N + 1) + d]
                + partial[((size_t)k * NWG + w) * N + d]
                + rank_local[i];
        sorted[(size_t)k * E + pos] = src_all[i];
    }
}

// ---------------- weight prep: transpose + bf16, combined biases ----------------
__global__ void prep_weights_kernel(const float* __restrict__ Wp,
                                    const float* __restrict__ Wc1, const float* __restrict__ Wc2,
                                    const float* __restrict__ bc1, const float* __restrict__ bc2,
                                    unsigned short* __restrict__ WpT,
                                    unsigned short* __restrict__ WcT,
                                    float* __restrict__ cbias) {
    int i = blockIdx.x * blockDim.x + threadIdx.x;
    int stride = gridDim.x * blockDim.x;
    const int nWp = 4 * 128 * 384;
    for (int p = i; p < nWp; p += stride) {
        int t = p / (128 * 384), rem = p % (128 * 384);
        int c = rem / 384, k = rem % 384;
        WpT[p] = f2b(Wp[(size_t)t * INF * HD + (size_t)k * HD + c]);
    }
    const int nWc = 5 * 128 * 128;
    for (int p = i; p < 2 * nWc; p += stride) {
        int layer = p / nWc, rem = p % nWc;
        int e = rem / (128 * 128), rem2 = rem % (128 * 128);
        int c = rem2 / 128, k = rem2 % 128;
        const float* W = layer ? Wc2 : Wc1;
        WcT[p] = f2b(W[(size_t)e * 128 * 128 + (size_t)k * 128 + c]);
    }
    // cbias[layer][t][c]: t0<-bc[4], t1<-bc[0], t2<-bc[2]+bc[3], t3<-bc[1]
    for (int p = i; p < 2 * 4 * 128; p += stride) {
        int layer = p / 512, rem = p % 512;
        int t = rem / 128, c = rem % 128;
        const float* bc = layer ? bc2 : bc1;
        float v;
        if (t == 0) v = bc[4 * 128 + c];
        else if (t == 1) v = bc[0 * 128 + c];
        else if (t == 2) v = bc[2 * 128 + c] + bc[3 * 128 + c];
        else v = bc[1 * 128 + c];
        cbias[p] = v;
    }
}

// ---------------- MFMA GEMM: out_bf16[M][128] = op( (A @ B) [*rowscale] [+rank1] [+bias] ) ----------------
template<int A_IS_F32>
__global__ __launch_bounds__(256) void gemm_mfma_kernel(
    const void* __restrict__ Araw, int lda,
    const unsigned short* __restrict__ Bt,
    const float* __restrict__ bias,
    const float* __restrict__ rowscale,
    const float* __restrict__ wlast,
    unsigned short* __restrict__ out,
    int M, int K, int relu)
{
    __shared__ __align__(16) unsigned short As[64][72];   // +8 pad: 144B row stride
    __shared__ __align__(16) unsigned short Bs[128][72];
    const int tid = threadIdx.x;
    const int bm = blockIdx.x * 64;
    const int wid = tid >> 6, lane = tid & 63;
    const int wr = wid & 1, wc = wid >> 1;      // 2x2 wave grid: 32 rows x 64 cols each
    const int l15 = lane & 15, l4 = lane >> 4;

    f32x4 acc[2][4] = {};

    for (int k0 = 0; k0 < K; k0 += 64) {
        if (A_IS_F32) {
            const float* A = (const float*)Araw;
            #pragma unroll
            for (int j = 0; j < 16; ++j) {
                int p = tid + j * 256;
                int r = p >> 6, c = p & 63;
                int gm = bm + r;
                float v = (gm < M) ? A[(size_t)gm * lda + k0 + c] : 0.f;
                As[r][c] = f2b(v);
            }
        } else {
            const unsigned short* A = (const unsigned short*)Araw;
            int r = tid >> 2, q = tid & 3;      // 16 bf16 per thread, vectorized
            int gm = bm + r;
            if (gm < M) {
                const uint4* g = (const uint4*)(A + (size_t)gm * lda + k0 + q * 16);
                *(uint4*)&As[r][q * 16] = g[0];
                *(uint4*)&As[r][q * 16 + 8] = g[1];
            } else {
                uint4 z = {0, 0, 0, 0};
                *(uint4*)&As[r][q * 16] = z;
                *(uint4*)&As[r][q * 16 + 8] = z;
            }
        }
        {
            int col = tid >> 1, hf = tid & 1;   // 32 bf16 per thread from Bt[col][k0+hf*32..]
            const uint4* g = (const uint4*)(Bt + (size_t)col * K + k0 + hf * 32);
            #pragma unroll
            for (int j = 0; j < 4; ++j)
                *(uint4*)&Bs[col][hf * 32 + j * 8] = g[j];
        }
        __syncthreads();
        #pragma unroll
        for (int kk = 0; kk < 2; ++kk) {
            short8 a[2], b[4];
            #pragma unroll
            for (int mi = 0; mi < 2; ++mi)
                a[mi] = *(const short8*)&As[wr * 32 + mi * 16 + l15][kk * 32 + l4 * 8];
            #pragma unroll
            for (int ni = 0; ni < 4; ++ni)
                b[ni] = *(const short8*)&Bs[wc * 64 + ni * 16 + l15][kk * 32 + l4 * 8];
            #pragma unroll
            for (int mi = 0; mi < 2; ++mi)
                #pragma unroll
                for (int ni = 0; ni < 4; ++ni)
                    acc[mi][ni] = __builtin_amdgcn_mfma_f32_16x16x32_bf16(
                        a[mi], b[ni], acc[mi][ni], 0, 0, 0);
        }
        __syncthreads();
    }

    // epilogue: C/D layout col=lane&15, row=(lane>>4)*4+reg  [m89-verified]
    #pragma unroll
    for (int mi = 0; mi < 2; ++mi) {
        #pragma unroll
        for (int r = 0; r < 4; ++r) {
            int grow = bm + wr * 32 + mi * 16 + l4 * 4 + r;
            if (grow >= M) continue;
            float rs = rowscale ? rowscale[grow] : 1.f;
            float al = 0.f;
            if (wlast && A_IS_F32) al = ((const float*)Araw)[(size_t)grow * lda + K];
            #pragma unroll
            for (int ni = 0; ni < 4; ++ni) {
                int gcol = wc * 64 + ni * 16 + l15;
                float v = acc[mi][ni][r];
                if (wlast) v += al * wlast[gcol];
                if (bias) v += bias[gcol];
                v *= rs;
                if (relu) v = fmaxf(v, 0.f);
                out[(size_t)grow * HD + gcol] = f2b(v);
            }
        }
    }
}

// ---------------- CSR gather: one wave per node, fp32 accum, fused bias+relu ----------------
template<int DUAL, int OUT_BF16>
__global__ __launch_bounds__(256) void gather_kernel(
    const unsigned short* __restrict__ msgA, const int* __restrict__ sortedA,
    const int* __restrict__ offA, const float* __restrict__ rsqA,
    const unsigned short* __restrict__ msgB, const int* __restrict__ sortedB,
    const int* __restrict__ offB, const float* __restrict__ rsqB,
    const float* __restrict__ bias, void* __restrict__ outv, int n)
{
    int node = blockIdx.x * 4 + (threadIdx.x >> 6);
    if (node >= n) return;
    int lane = threadIdx.x & 63;

    float ox, oy;
    {
        float ax = 0.f, ay = 0.f;
        int beg = offA[node], end = offA[node + 1];
        int e = beg;
        for (; e + 1 < end; e += 2) {
            int s0 = sortedA[e], s1 = sortedA[e + 1];
            unsigned int v0 = *(const unsigned int*)(msgA + (size_t)s0 * HD + lane * 2);
            unsigned int v1 = *(const unsigned int*)(msgA + (size_t)s1 * HD + lane * 2);
            ax += b2f(v0 & 0xffffu) + b2f(v1 & 0xffffu);
            ay += b2f(v0 >> 16) + b2f(v1 >> 16);
        }
        if (e < end) {
            int s0 = sortedA[e];
            unsigned int v0 = *(const unsigned int*)(msgA + (size_t)s0 * HD + lane * 2);
            ax += b2f(v0 & 0xffffu);
            ay += b2f(v0 >> 16);
        }
        float r = rsqA[node];
        ox = ax * r; oy = ay * r;
    }
    if (DUAL) {
        float bx = 0.f, by = 0.f;
        int beg = offB[node], end = offB[node + 1];
        int e = beg;
        for (; e + 1 < end; e += 2) {
            int s0 = sortedB[e], s1 = sortedB[e + 1];
            unsigned int v0 = *(const unsigned int*)(msgB + (size_t)s0 * HD + lane * 2);
            unsigned int v1 = *(const unsigned int*)(msgB + (size_t)s1 * HD + lane * 2);
            bx += b2f(v0 & 0xffffu) + b2f(v1 & 0xffffu);
            by += b2f(v0 >> 16) + b2f(v1 >> 16);
        }
        if (e < end) {
            int s0 = sortedB[e];
            unsigned int v0 = *(const unsigned int*)(msgB + (size_t)s0 * HD + lane * 2);
            bx += b2f(v0 & 0xffffu);
            by += b2f(v0 >> 16);
        }
        float r = rsqB[node];
        ox += bx * r; oy += by * r;
    }
    float2 bv = *(const float2*)(bias + lane * 2);
    ox = fmaxf(ox + bv.x, 0.f);
    oy = fmaxf(oy + bv.y, 0.f);
    if (OUT_BF16) {
        unsigned int packed = ((unsigned int)f2b(oy) << 16) | f2b(ox);
        ((unsigned int*)outv)[(size_t)node * (HD / 2) + lane] = packed;
    } else {
        float2 o = {ox, oy};
        ((float2*)outv)[(size_t)node * (HD / 2) + lane] = o;
    }
}

extern "C" void kernel_launch(void* const* d_in, const int* in_sizes, int n_in,
                              void* d_out, int out_size, void* d_ws, size_t ws_size,
                              hipStream_t stream)
{
    const float* feat[4] = {(const float*)d_in[0], (const float*)d_in[1],
                            (const float*)d_in[2], (const float*)d_in[3]};
    const int* src_all = (const int*)d_in[4];
    const int* dst_all = (const int*)d_in[5];
    const float* Wp  = (const float*)d_in[6];
    const float* bp  = (const float*)d_in[7];
    const float* Wc1 = (const float*)d_in[8];
    const float* bc1 = (const float*)d_in[9];
    const float* Wc2 = (const float*)d_in[10];
    const float* bc2 = (const float*)d_in[11];

    const int N = in_sizes[0] / INF;      // 50000
    const int E = in_sizes[4] / 5;        // 1,600,000

    // etypes: k -> (src_type, dst_type): (0,1) (1,3) (3,2) (0,2) (2,0)
    const int st_[5] = {0, 1, 3, 0, 2};

    // ---- workspace layout (all offsets 256B-aligned) ----
    char* w = (char*)d_ws;
    auto take = [&](size_t bytes) { char* p = w; w += (bytes + 255) & ~(size_t)255; return p; };
    int*   cnt_dst = (int*)take(5 * (size_t)N * 4);
    float* rsq_out = (float*)take(5 * (size_t)N * 4);
    float* rsq_in  = (float*)take(5 * (size_t)N * 4);
    int*   off     = (int*)take(5 * (size_t)(N + 1) * 4);
    int*   sorted  = (int*)take(5 * (size_t)E * 4);
    int*   partial = (int*)take(10 * (size_t)NWG * N * 4);       // 16 MB
    unsigned short* rank_local = (unsigned short*)take(5 * (size_t)E * 2); // 16 MB
    unsigned short* WpT = (unsigned short*)take(4 * 128 * 384 * 2);
    unsigned short* WcT = (unsigned short*)take(2 * 5 * 128 * 128 * 2);
    float* cbias   = (float*)take(2 * 4 * 128 * 4);
    unsigned short* h1   = (unsigned short*)take(4 * (size_t)N * HD * 2);
    unsigned short* msg0 = (unsigned short*)take((size_t)N * HD * 2);
    unsigned short* msg1 = (unsigned short*)take((size_t)N * HD * 2);
    unsigned short* h0 = (unsigned short*)d_out;   // dead before layer-2 output writes

    // ---- prep: weights + CSR (no device-scope atomics anywhere) ----
    prep_weights_kernel<<<512, 256, 0, stream>>>(Wp, Wc1, Wc2, bc1, bc2, WpT, WcT, cbias);
    hist_kernel<<<10 * NWG, 1024, 0, stream>>>(src_all, dst_all, partial, rank_local, E, N);
    reduce_kernel<<<(10 * N + 255) / 256, 256, 0, stream>>>(partial, cnt_dst, rsq_out, rsq_in, N);
    scan_kernel<<<5, 1024, 0, stream>>>(cnt_dst, off, N);
    permute_kernel<<<2048, 256, 0, stream>>>(src_all, dst_all, off, partial, rank_local,
                                             sorted, E, N);

    const int gblk = (N + 63) / 64;

    // ---- input projections: h0[t] = relu(feat[t](f32) @ WpT[t] + rank1 + bp[t]) ----
    for (int t = 0; t < 4; ++t) {
        gemm_mfma_kernel<1><<<gblk, 256, 0, stream>>>(
            feat[t], INF, WpT + (size_t)t * 128 * 384,
            bp + (size_t)t * HD, nullptr,
            Wp + (size_t)t * INF * HD + 384 * HD,   // wlast = Wp[t][384][:]
            h0 + (size_t)t * N * HD, N, 384, 1);
    }

    // ---- 2 hetero conv layers ----
    for (int layer = 0; layer < 2; ++layer) {
        const unsigned short* hin = layer ? h1 : h0;
        const unsigned short* WT = WcT + (size_t)layer * 5 * 128 * 128;
        const float* cb = cbias + (size_t)layer * 4 * 128;
        void* outp = layer ? (void*)d_out : (void*)h1;
        const int OUTB = layer ? 0 : 1;

        auto conv_gemm = [&](int k, unsigned short* m) {
            gemm_mfma_kernel<0><<<gblk, 256, 0, stream>>>(
                hin + (size_t)st_[k] * N * HD, HD, WT + (size_t)k * 128 * 128,
                nullptr, rsq_out + (size_t)k * N, nullptr, m, N, 128, 0);
        };
        auto out_t = [&](int t) -> void* {
            return (char*)outp + (size_t)t * N * HD * (OUTB ? 2 : 4);
        };
        const int gg = (N + 3) / 4;

        // k=0: t0 -> t1
        conv_gemm(0, msg0);
        if (OUTB) gather_kernel<0, 1><<<gg, 256, 0, stream>>>(
            msg0, sorted + 0 * (size_t)E, off + 0 * (size_t)(N + 1), rsq_in + 0 * (size_t)N,
            nullptr, nullptr, nullptr, nullptr, cb + 1 * HD, out_t(1), N);
        else gather_kernel<0, 0><<<gg, 256, 0, stream>>>(
            msg0, sorted + 0 * (size_t)E, off + 0 * (size_t)(N + 1), rsq_in + 0 * (size_t)N,
            nullptr, nullptr, nullptr, nullptr, cb + 1 * HD, out_t(1), N);

        // k=1: t1 -> t3
        conv_gemm(1, msg0);
        if (OUTB) gather_kernel<0, 1><<<gg, 256, 0, stream>>>(
            msg0, sorted + 1 * (size_t)E, off + 1 * (size_t)(N + 1), rsq_in + 1 * (size_t)N,
            nullptr, nullptr, nullptr, nullptr, cb + 3 * HD, out_t(3), N);
        else gather_kernel<0, 0><<<gg, 256, 0, stream>>>(
            msg0, sorted + 1 * (size_t)E, off + 1 * (size_t)(N + 1), rsq_in + 1 * (size_t)N,
            nullptr, nullptr, nullptr, nullptr, cb + 3 * HD, out_t(3), N);

        // k=2 (t3->t2) + k=3 (t0->t2): dual gather
        conv_gemm(2, msg0);
        conv_gemm(3, msg1);
        if (OUTB) gather_kernel<1, 1><<<gg, 256, 0, stream>>>(
            msg0, sorted + 2 * (size_t)E, off + 2 * (size_t)(N + 1), rsq_in + 2 * (size_t)N,
            msg1, sorted + 3 * (size_t)E, off + 3 * (size_t)(N + 1), rsq_in + 3 * (size_t)N,
            cb + 2 * HD, out_t(2), N);
        else gather_kernel<1, 0><<<gg, 256, 0, stream>>>(
            msg0, sorted + 2 * (size_t)E, off + 2 * (size_t)(N + 1), rsq_in + 2 * (size_t)N,
            msg1, sorted + 3 * (size_t)E, off + 3 * (size_t)(N + 1), rsq_in + 3 * (size_t)N,
            cb + 2 * HD, out_t(2), N);

        // k=4: t2 -> t0
        conv_gemm(4, msg0);
        if (OUTB) gather_kernel<0, 1><<<gg, 256, 0, stream>>>(
            msg0, sorted + 4 * (size_t)E, off + 4 * (size_t)(N + 1), rsq_in + 4 * (size_t)N,
            nullptr, nullptr, nullptr, nullptr, cb + 0 * HD, out_t(0), N);
        else gather_kernel<0, 0><<<gg, 256, 0, stream>>>(
            msg0, sorted + 4 * (size_t)E, off + 4 * (size_t)(N + 1), rsq_in + 4 * (size_t)N,
            nullptr, nullptr, nullptr, nullptr, cb + 0 * HD, out_t(0), N);
    }
}

// Round 6
// 1380.592 us; speedup vs baseline: 20.9937x; 1.2217x over previous
//
#include <hip/hip_runtime.h>
#include <hip/hip_bf16.h>

#define INF 385
#define HD 128
#define NWG 16   // workgroups per histogram group

typedef __attribute__((ext_vector_type(8))) short short8;
typedef __attribute__((ext_vector_type(4))) float f32x4;

__device__ inline unsigned short f2b(float f) {
    __hip_bfloat16 h = __float2bfloat16(f);
    return *reinterpret_cast<unsigned short*>(&h);
}
__device__ inline float b2f(unsigned int lo16) {
    union { unsigned int u; float f; } c; c.u = lo16 << 16; return c.f;
}

// ---------------- LDS-privatized histogram + in-chunk ranks (no device atomics) ----------------
// grid = 10 groups * NWG; group g<5: dst side of etype g (writes rank_local);
// g>=5: src side of etype g-5.
__global__ __launch_bounds__(1024) void hist_kernel(
    const int* __restrict__ src_all, const int* __restrict__ dst_all,
    unsigned short* __restrict__ partial,    // [10][NWG][N]
    unsigned short* __restrict__ rank_local, // [5][E]
    int E, int N)
{
    __shared__ unsigned int cnt[25000];      // 2 packed ushort counters per uint
    int g = blockIdx.x / NWG;
    int w = blockIdx.x % NWG;
    int tid = threadIdx.x;
    int half = (N + 1) / 2;
    for (int i = tid; i < half; i += 1024) cnt[i] = 0;
    __syncthreads();

    int C = (E + NWG - 1) / NWG;
    int lo = w * C, hi = min(lo + C, E);
    if (g < 5) {
        const int* arr = dst_all + (size_t)g * E;
        for (int e = lo + tid; e < hi; e += 1024) {
            int d = __builtin_nontemporal_load(&arr[e]);
            unsigned int sh = (d & 1) * 16;
            unsigned int old = atomicAdd(&cnt[d >> 1], 1u << sh);
            rank_local[(size_t)g * E + e] = (unsigned short)((old >> sh) & 0xffffu);
        }
    } else {
        const int* arr = src_all + (size_t)(g - 5) * E;
        for (int e = lo + tid; e < hi; e += 1024) {
            int d = __builtin_nontemporal_load(&arr[e]);
            atomicAdd(&cnt[d >> 1], 1u << ((d & 1) * 16));
        }
    }
    __syncthreads();
    unsigned short* outp = partial + ((size_t)g * NWG + w) * N;
    for (int n = tid; n < N; n += 1024)
        outp[n] = (unsigned short)((cnt[n >> 1] >> ((n & 1) * 16)) & 0xffffu);
}

// ---------------- reduce partials -> degrees/rsqrt; in-place exclusive prefix over chunks ----------------
__global__ void reduce_kernel(unsigned short* __restrict__ partial, int* __restrict__ cnt_dst,
                              float* __restrict__ rsq_out, float* __restrict__ rsq_in, int N) {
    int i = blockIdx.x * blockDim.x + threadIdx.x;
    int stride = gridDim.x * blockDim.x;
    int tot = 10 * N;
    for (; i < tot; i += stride) {
        int g = i / N, n = i - g * N;
        unsigned short* p = partial + ((size_t)g * NWG) * N + n;
        int sum = 0;
        #pragma unroll
        for (int w = 0; w < NWG; ++w) {
            int v = p[(size_t)w * N];
            p[(size_t)w * N] = (unsigned short)sum;   // exclusive prefix (rank base per chunk)
            sum += v;
        }
        float r = rsqrtf((float)max(sum, 1));
        if (g < 5) { cnt_dst[i] = sum; rsq_in[i] = r; }
        else rsq_out[i - 5 * N] = r;
    }
}

// 5 blocks, one per etype
__global__ __launch_bounds__(1024) void scan_kernel(const int* __restrict__ cnt_all,
                                                    int* __restrict__ off_all, int n) {
    const int* cnt = cnt_all + (size_t)blockIdx.x * n;
    int* off = off_all + (size_t)blockIdx.x * (n + 1);
    __shared__ int ssum[1024];
    int t = threadIdx.x;
    int chunk = (n + 1023) / 1024;
    int lo = t * chunk, hi = min(lo + chunk, n);
    int s = 0;
    for (int i = lo; i < hi; ++i) s += cnt[i];
    ssum[t] = s;
    __syncthreads();
    for (int d = 1; d < 1024; d <<= 1) {
        int v = (t >= d) ? ssum[t - d] : 0;
        __syncthreads();
        ssum[t] += v;
        __syncthreads();
    }
    int excl = (t == 0) ? 0 : ssum[t - 1];
    for (int i = lo; i < hi; ++i) { off[i] = excl; excl += cnt[i]; }
    if (t == 1023) off[n] = ssum[1023];
}

// ---------------- atomic-free permutation: sorted_src (ushort) grouped by dst ----------------
__global__ void permute_kernel(const int* __restrict__ src_all, const int* __restrict__ dst_all,
                               const int* __restrict__ off, const unsigned short* __restrict__ partial,
                               const unsigned short* __restrict__ rank_local,
                               unsigned short* __restrict__ sorted, int E, int N) {
    int i = blockIdx.x * blockDim.x + threadIdx.x;
    int stride = gridDim.x * blockDim.x;
    int tot = 5 * E;
    int C = (E + NWG - 1) / NWG;
    for (; i < tot; i += stride) {
        int k = i / E, e = i - k * E;
        int w = e / C;
        int d = __builtin_nontemporal_load(&dst_all[i]);
        int s = __builtin_nontemporal_load(&src_all[i]);
        int rl = __builtin_nontemporal_load(&rank_local[i]);
        int pos = off[(size_t)k * (N + 1) + d]
                + partial[((size_t)k * NWG + w) * N + d]
                + rl;
        __builtin_nontemporal_store((unsigned short)s, &sorted[(size_t)k * E + pos]);
    }
}

// ---------------- weight prep: transpose + bf16, combined biases ----------------
__global__ void prep_weights_kernel(const float* __restrict__ Wp,
                                    const float* __restrict__ Wc1, const float* __restrict__ Wc2,
                                    const float* __restrict__ bc1, const float* __restrict__ bc2,
                                    unsigned short* __restrict__ WpT,
                                    unsigned short* __restrict__ WcT,
                                    float* __restrict__ cbias) {
    int i = blockIdx.x * blockDim.x + threadIdx.x;
    int stride = gridDim.x * blockDim.x;
    const int nWp = 4 * 128 * 384;
    for (int p = i; p < nWp; p += stride) {
        int t = p / (128 * 384), rem = p % (128 * 384);
        int c = rem / 384, k = rem % 384;
        WpT[p] = f2b(Wp[(size_t)t * INF * HD + (size_t)k * HD + c]);
    }
    const int nWc = 5 * 128 * 128;
    for (int p = i; p < 2 * nWc; p += stride) {
        int layer = p / nWc, rem = p % nWc;
        int e = rem / (128 * 128), rem2 = rem % (128 * 128);
        int c = rem2 / 128, k = rem2 % 128;
        const float* W = layer ? Wc2 : Wc1;
        WcT[p] = f2b(W[(size_t)e * 128 * 128 + (size_t)k * 128 + c]);
    }
    // cbias[layer][t][c]: t0<-bc[4], t1<-bc[0], t2<-bc[2]+bc[3], t3<-bc[1]
    for (int p = i; p < 2 * 4 * 128; p += stride) {
        int layer = p / 512, rem = p % 512;
        int t = rem / 128, c = rem % 128;
        const float* bc = layer ? bc2 : bc1;
        float v;
        if (t == 0) v = bc[4 * 128 + c];
        else if (t == 1) v = bc[0 * 128 + c];
        else if (t == 2) v = bc[2 * 128 + c] + bc[3 * 128 + c];
        else v = bc[1 * 128 + c];
        cbias[p] = v;
    }
}

// ---------------- batched MFMA GEMM ----------------
struct GemmDesc {
    const void* A;
    const unsigned short* Bt;
    const float* bias;
    const float* rowscale;
    const float* wlast;
    unsigned short* out;
};
struct GemmBatch { GemmDesc d[5]; };

template<int A_IS_F32>
__global__ __launch_bounds__(256) void gemm_mfma_kernel(
    GemmBatch batch, int lda, int M, int K, int relu)
{
    const GemmDesc dsc = batch.d[blockIdx.y];
    const unsigned short* __restrict__ Bt = dsc.Bt;

    __shared__ __align__(16) unsigned short As[64][72];   // +8 pad: 144B row stride
    __shared__ __align__(16) unsigned short Bs[128][72];
    const int tid = threadIdx.x;
    const int bm = blockIdx.x * 64;
    const int wid = tid >> 6, lane = tid & 63;
    const int wr = wid & 1, wc = wid >> 1;      // 2x2 wave grid: 32 rows x 64 cols each
    const int l15 = lane & 15, l4 = lane >> 4;

    f32x4 acc[2][4] = {};

    for (int k0 = 0; k0 < K; k0 += 64) {
        if (A_IS_F32) {
            const float* A = (const float*)dsc.A;
            #pragma unroll
            for (int j = 0; j < 16; ++j) {
                int p = tid + j * 256;
                int r = p >> 6, c = p & 63;
                int gm = bm + r;
                float v = (gm < M) ? A[(size_t)gm * lda + k0 + c] : 0.f;
                As[r][c] = f2b(v);
            }
        } else {
            const unsigned short* A = (const unsigned short*)dsc.A;
            int r = tid >> 2, q = tid & 3;      // 16 bf16 per thread, vectorized
            int gm = bm + r;
            if (gm < M) {
                const uint4* g = (const uint4*)(A + (size_t)gm * lda + k0 + q * 16);
                *(uint4*)&As[r][q * 16] = g[0];
                *(uint4*)&As[r][q * 16 + 8] = g[1];
            } else {
                uint4 z = {0, 0, 0, 0};
                *(uint4*)&As[r][q * 16] = z;
                *(uint4*)&As[r][q * 16 + 8] = z;
            }
        }
        {
            int col = tid >> 1, hf = tid & 1;   // 32 bf16 per thread from Bt[col][k0+hf*32..]
            const uint4* g = (const uint4*)(Bt + (size_t)col * K + k0 + hf * 32);
            #pragma unroll
            for (int j = 0; j < 4; ++j)
                *(uint4*)&Bs[col][hf * 32 + j * 8] = g[j];
        }
        __syncthreads();
        #pragma unroll
        for (int kk = 0; kk < 2; ++kk) {
            short8 a[2], b[4];
            #pragma unroll
            for (int mi = 0; mi < 2; ++mi)
                a[mi] = *(const short8*)&As[wr * 32 + mi * 16 + l15][kk * 32 + l4 * 8];
            #pragma unroll
            for (int ni = 0; ni < 4; ++ni)
                b[ni] = *(const short8*)&Bs[wc * 64 + ni * 16 + l15][kk * 32 + l4 * 8];
            #pragma unroll
            for (int mi = 0; mi < 2; ++mi)
                #pragma unroll
                for (int ni = 0; ni < 4; ++ni)
                    acc[mi][ni] = __builtin_amdgcn_mfma_f32_16x16x32_bf16(
                        a[mi], b[ni], acc[mi][ni], 0, 0, 0);
        }
        __syncthreads();
    }

    // epilogue: C/D layout col=lane&15, row=(lane>>4)*4+reg  [m89-verified]
    #pragma unroll
    for (int mi = 0; mi < 2; ++mi) {
        #pragma unroll
        for (int r = 0; r < 4; ++r) {
            int grow = bm + wr * 32 + mi * 16 + l4 * 4 + r;
            if (grow >= M) continue;
            float rs = dsc.rowscale ? dsc.rowscale[grow] : 1.f;
            float al = 0.f;
            if (dsc.wlast && A_IS_F32) al = ((const float*)dsc.A)[(size_t)grow * lda + K];
            #pragma unroll
            for (int ni = 0; ni < 4; ++ni) {
                int gcol = wc * 64 + ni * 16 + l15;
                float v = acc[mi][ni][r];
                if (dsc.wlast) v += al * dsc.wlast[gcol];
                if (dsc.bias) v += dsc.bias[gcol];
                v *= rs;
                if (relu) v = fmaxf(v, 0.f);
                dsc.out[(size_t)grow * HD + gcol] = f2b(v);
            }
        }
    }
}

// ---------------- CSR gather: one wave per node, fp32 accum, fused bias+relu ----------------
template<int DUAL, int OUT_BF16>
__global__ __launch_bounds__(256) void gather_kernel(
    const unsigned short* __restrict__ msgA, const unsigned short* __restrict__ sortedA,
    const int* __restrict__ offA, const float* __restrict__ rsqA,
    const unsigned short* __restrict__ msgB, const unsigned short* __restrict__ sortedB,
    const int* __restrict__ offB, const float* __restrict__ rsqB,
    const float* __restrict__ bias, void* __restrict__ outv, int n)
{
    int node = blockIdx.x * 4 + (threadIdx.x >> 6);
    if (node >= n) return;
    int lane = threadIdx.x & 63;

    float ox, oy;
    {
        float ax = 0.f, ay = 0.f;
        int beg = offA[node], end = offA[node + 1];
        int e = beg;
        for (; e + 3 < end; e += 4) {
            int s0 = sortedA[e], s1 = sortedA[e + 1];
            int s2 = sortedA[e + 2], s3 = sortedA[e + 3];
            unsigned int v0 = *(const unsigned int*)(msgA + (size_t)s0 * HD + lane * 2);
            unsigned int v1 = *(const unsigned int*)(msgA + (size_t)s1 * HD + lane * 2);
            unsigned int v2 = *(const unsigned int*)(msgA + (size_t)s2 * HD + lane * 2);
            unsigned int v3 = *(const unsigned int*)(msgA + (size_t)s3 * HD + lane * 2);
            ax += b2f(v0 & 0xffffu) + b2f(v1 & 0xffffu) + b2f(v2 & 0xffffu) + b2f(v3 & 0xffffu);
            ay += b2f(v0 >> 16) + b2f(v1 >> 16) + b2f(v2 >> 16) + b2f(v3 >> 16);
        }
        for (; e < end; ++e) {
            int s0 = sortedA[e];
            unsigned int v0 = *(const unsigned int*)(msgA + (size_t)s0 * HD + lane * 2);
            ax += b2f(v0 & 0xffffu);
            ay += b2f(v0 >> 16);
        }
        float r = rsqA[node];
        ox = ax * r; oy = ay * r;
    }
    if (DUAL) {
        float bx = 0.f, by = 0.f;
        int beg = offB[node], end = offB[node + 1];
        int e = beg;
        for (; e + 3 < end; e += 4) {
            int s0 = sortedB[e], s1 = sortedB[e + 1];
            int s2 = sortedB[e + 2], s3 = sortedB[e + 3];
            unsigned int v0 = *(const unsigned int*)(msgB + (size_t)s0 * HD + lane * 2);
            unsigned int v1 = *(const unsigned int*)(msgB + (size_t)s1 * HD + lane * 2);
            unsigned int v2 = *(const unsigned int*)(msgB + (size_t)s2 * HD + lane * 2);
            unsigned int v3 = *(const unsigned int*)(msgB + (size_t)s3 * HD + lane * 2);
            bx += b2f(v0 & 0xffffu) + b2f(v1 & 0xffffu) + b2f(v2 & 0xffffu) + b2f(v3 & 0xffffu);
            by += b2f(v0 >> 16) + b2f(v1 >> 16) + b2f(v2 >> 16) + b2f(v3 >> 16);
        }
        for (; e < end; ++e) {
            int s0 = sortedB[e];
            unsigned int v0 = *(const unsigned int*)(msgB + (size_t)s0 * HD + lane * 2);
            bx += b2f(v0 & 0xffffu);
            by += b2f(v0 >> 16);
        }
        float r = rsqB[node];
        ox += bx * r; oy += by * r;
    }
    float2 bv = *(const float2*)(bias + lane * 2);
    ox = fmaxf(ox + bv.x, 0.f);
    oy = fmaxf(oy + bv.y, 0.f);
    if (OUT_BF16) {
        unsigned int packed = ((unsigned int)f2b(oy) << 16) | f2b(ox);
        ((unsigned int*)outv)[(size_t)node * (HD / 2) + lane] = packed;
    } else {
        float2 o = {ox, oy};
        ((float2*)outv)[(size_t)node * (HD / 2) + lane] = o;
    }
}

extern "C" void kernel_launch(void* const* d_in, const int* in_sizes, int n_in,
                              void* d_out, int out_size, void* d_ws, size_t ws_size,
                              hipStream_t stream)
{
    const float* feat[4] = {(const float*)d_in[0], (const float*)d_in[1],
                            (const float*)d_in[2], (const float*)d_in[3]};
    const int* src_all = (const int*)d_in[4];
    const int* dst_all = (const int*)d_in[5];
    const float* Wp  = (const float*)d_in[6];
    const float* bp  = (const float*)d_in[7];
    const float* Wc1 = (const float*)d_in[8];
    const float* bc1 = (const float*)d_in[9];
    const float* Wc2 = (const float*)d_in[10];
    const float* bc2 = (const float*)d_in[11];

    const int N = in_sizes[0] / INF;      // 50000  (< 65536: ushort ids)
    const int E = in_sizes[4] / 5;        // 1,600,000

    // etypes: k -> (src_type, dst_type): (0,1) (1,3) (3,2) (0,2) (2,0)
    const int st_[5] = {0, 1, 3, 0, 2};

    // ---- workspace layout (all offsets 256B-aligned) ----
    char* w = (char*)d_ws;
    auto take = [&](size_t bytes) { char* p = w; w += (bytes + 255) & ~(size_t)255; return p; };
    int*   cnt_dst = (int*)take(5 * (size_t)N * 4);
    float* rsq_out = (float*)take(5 * (size_t)N * 4);
    float* rsq_in  = (float*)take(5 * (size_t)N * 4);
    int*   off     = (int*)take(5 * (size_t)(N + 1) * 4);
    unsigned short* sorted  = (unsigned short*)take(5 * (size_t)E * 2);      // 16 MB
    unsigned short* partial = (unsigned short*)take(10 * (size_t)NWG * N * 2); // 16 MB
    unsigned short* rank_local = (unsigned short*)take(5 * (size_t)E * 2);   // 16 MB
    unsigned short* WpT = (unsigned short*)take(4 * 128 * 384 * 2);
    unsigned short* WcT = (unsigned short*)take(2 * 5 * 128 * 128 * 2);
    float* cbias   = (float*)take(2 * 4 * 128 * 4);
    unsigned short* h1   = (unsigned short*)take(4 * (size_t)N * HD * 2);
    unsigned short* msg0 = (unsigned short*)take((size_t)N * HD * 2);
    unsigned short* msg1 = (unsigned short*)take((size_t)N * HD * 2);
    unsigned short* h0 = (unsigned short*)d_out;   // dead before layer-2 output writes

    // ---- prep: weights + CSR (no device-scope atomics anywhere) ----
    prep_weights_kernel<<<512, 256, 0, stream>>>(Wp, Wc1, Wc2, bc1, bc2, WpT, WcT, cbias);
    hist_kernel<<<10 * NWG, 1024, 0, stream>>>(src_all, dst_all, partial, rank_local, E, N);
    reduce_kernel<<<(10 * N + 255) / 256, 256, 0, stream>>>(partial, cnt_dst, rsq_out, rsq_in, N);
    scan_kernel<<<5, 1024, 0, stream>>>(cnt_dst, off, N);
    permute_kernel<<<2048, 256, 0, stream>>>(src_all, dst_all, off, partial, rank_local,
                                             sorted, E, N);

    const int gblk = (N + 63) / 64;

    // ---- input projections (batched over 4 types): h0[t] = relu(feat[t] @ WpT[t] + rank1 + bp[t]) ----
    {
        GemmBatch pb = {};
        for (int t = 0; t < 4; ++t) {
            pb.d[t].A = feat[t];
            pb.d[t].Bt = WpT + (size_t)t * 128 * 384;
            pb.d[t].bias = bp + (size_t)t * HD;
            pb.d[t].rowscale = nullptr;
            pb.d[t].wlast = Wp + (size_t)t * INF * HD + 384 * HD;
            pb.d[t].out = h0 + (size_t)t * N * HD;
        }
        gemm_mfma_kernel<1><<<dim3(gblk, 4), 256, 0, stream>>>(pb, INF, N, 384, 1);
    }

    // ---- 2 hetero conv layers ----
    for (int layer = 0; layer < 2; ++layer) {
        const unsigned short* hin = layer ? h1 : h0;
        const unsigned short* WT = WcT + (size_t)layer * 5 * 128 * 128;
        const float* cb = cbias + (size_t)layer * 4 * 128;
        void* outp = layer ? (void*)d_out : (void*)h1;
        const int OUTB = layer ? 0 : 1;

        auto conv_gemm = [&](int k, unsigned short* m) {
            GemmBatch cbch = {};
            cbch.d[0].A = hin + (size_t)st_[k] * N * HD;
            cbch.d[0].Bt = WT + (size_t)k * 128 * 128;
            cbch.d[0].bias = nullptr;
            cbch.d[0].rowscale = rsq_out + (size_t)k * N;
            cbch.d[0].wlast = nullptr;
            cbch.d[0].out = m;
            gemm_mfma_kernel<0><<<dim3(gblk, 1), 256, 0, stream>>>(cbch, HD, N, 128, 0);
        };
        auto out_t = [&](int t) -> void* {
            return (char*)outp + (size_t)t * N * HD * (OUTB ? 2 : 4);
        };
        const int gg = (N + 3) / 4;

        // k=0: t0 -> t1
        conv_gemm(0, msg0);
        if (OUTB) gather_kernel<0, 1><<<gg, 256, 0, stream>>>(
            msg0, sorted + 0 * (size_t)E, off + 0 * (size_t)(N + 1), rsq_in + 0 * (size_t)N,
            nullptr, nullptr, nullptr, nullptr, cb + 1 * HD, out_t(1), N);
        else gather_kernel<0, 0><<<gg, 256, 0, stream>>>(
            msg0, sorted + 0 * (size_t)E, off + 0 * (size_t)(N + 1), rsq_in + 0 * (size_t)N,
            nullptr, nullptr, nullptr, nullptr, cb + 1 * HD, out_t(1), N);

        // k=1: t1 -> t3
        conv_gemm(1, msg0);
        if (OUTB) gather_kernel<0, 1><<<gg, 256, 0, stream>>>(
            msg0, sorted + 1 * (size_t)E, off + 1 * (size_t)(N + 1), rsq_in + 1 * (size_t)N,
            nullptr, nullptr, nullptr, nullptr, cb + 3 * HD, out_t(3), N);
        else gather_kernel<0, 0><<<gg, 256, 0, stream>>>(
            msg0, sorted + 1 * (size_t)E, off + 1 * (size_t)(N + 1), rsq_in + 1 * (size_t)N,
            nullptr, nullptr, nullptr, nullptr, cb + 3 * HD, out_t(3), N);

        // k=2 (t3->t2) + k=3 (t0->t2): dual gather
        conv_gemm(2, msg0);
        conv_gemm(3, msg1);
        if (OUTB) gather_kernel<1, 1><<<gg, 256, 0, stream>>>(
            msg0, sorted + 2 * (size_t)E, off + 2 * (size_t)(N + 1), rsq_in + 2 * (size_t)N,
            msg1, sorted + 3 * (size_t)E, off + 3 * (size_t)(N + 1), rsq_in + 3 * (size_t)N,
            cb + 2 * HD, out_t(2), N);
        else gather_kernel<1, 0><<<gg, 256, 0, stream>>>(
            msg0, sorted + 2 * (size_t)E, off + 2 * (size_t)(N + 1), rsq_in + 2 * (size_t)N,
            msg1, sorted + 3 * (size_t)E, off + 3 * (size_t)(N + 1), rsq_in + 3 * (size_t)N,
            cb + 2 * HD, out_t(2), N);

        // k=4: t2 -> t0
        conv_gemm(4, msg0);
        if (OUTB) gather_kernel<0, 1><<<gg, 256, 0, stream>>>(
            msg0, sorted + 4 * (size_t)E, off + 4 * (size_t)(N + 1), rsq_in + 4 * (size_t)N,
            nullptr, nullptr, nullptr, nullptr, cb + 0 * HD, out_t(0), N);
        else gather_kernel<0, 0><<<gg, 256, 0, stream>>>(
            msg0, sorted + 4 * (size_t)E, off + 4 * (size_t)(N + 1), rsq_in + 4 * (size_t)N,
            nullptr, nullptr, nullptr, nullptr, cb + 0 * HD, out_t(0), N);
    }
}

// Round 7
// 1191.763 us; speedup vs baseline: 24.3200x; 1.1584x over previous
//
#include <hip/hip_runtime.h>
#include <hip/hip_bf16.h>

#define INF 385
#define HD 128
#define NWG 16   // workgroups per histogram group

typedef __attribute__((ext_vector_type(8))) short short8;
typedef __attribute__((ext_vector_type(4))) float f32x4;

__device__ inline unsigned short f2b(float f) {
    __hip_bfloat16 h = __float2bfloat16(f);
    return *reinterpret_cast<unsigned short*>(&h);
}
__device__ inline float b2f(unsigned int lo16) {
    union { unsigned int u; float f; } c; c.u = lo16 << 16; return c.f;
}

// ---------------- LDS-privatized histogram + in-chunk ranks (no device atomics) ----------------
__global__ __launch_bounds__(1024) void hist_kernel(
    const int* __restrict__ src_all, const int* __restrict__ dst_all,
    unsigned short* __restrict__ partial,    // [10][NWG][N]
    unsigned short* __restrict__ rank_local, // [5][E]
    int E, int N)
{
    __shared__ unsigned int cnt[25000];      // 2 packed ushort counters per uint
    int g = blockIdx.x / NWG;
    int w = blockIdx.x % NWG;
    int tid = threadIdx.x;
    int half = (N + 1) / 2;
    for (int i = tid; i < half; i += 1024) cnt[i] = 0;
    __syncthreads();

    int C = (E + NWG - 1) / NWG;
    int lo = w * C, hi = min(lo + C, E);
    if (g < 5) {
        const int* arr = dst_all + (size_t)g * E;
        for (int e = lo + tid; e < hi; e += 1024) {
            int d = __builtin_nontemporal_load(&arr[e]);
            unsigned int sh = (d & 1) * 16;
            unsigned int old = atomicAdd(&cnt[d >> 1], 1u << sh);
            rank_local[(size_t)g * E + e] = (unsigned short)((old >> sh) & 0xffffu);
        }
    } else {
        const int* arr = src_all + (size_t)(g - 5) * E;
        for (int e = lo + tid; e < hi; e += 1024) {
            int d = __builtin_nontemporal_load(&arr[e]);
            atomicAdd(&cnt[d >> 1], 1u << ((d & 1) * 16));
        }
    }
    __syncthreads();
    unsigned short* outp = partial + ((size_t)g * NWG + w) * N;
    for (int n = tid; n < N; n += 1024)
        outp[n] = (unsigned short)((cnt[n >> 1] >> ((n & 1) * 16)) & 0xffffu);
}

// ---------------- reduce partials -> degrees/rsqrt; in-place exclusive prefix over chunks ----------------
__global__ void reduce_kernel(unsigned short* __restrict__ partial, int* __restrict__ cnt_dst,
                              float* __restrict__ rsq_out, float* __restrict__ rsq_in, int N) {
    int i = blockIdx.x * blockDim.x + threadIdx.x;
    int stride = gridDim.x * blockDim.x;
    int tot = 10 * N;
    for (; i < tot; i += stride) {
        int g = i / N, n = i - g * N;
        unsigned short* p = partial + ((size_t)g * NWG) * N + n;
        int sum = 0;
        #pragma unroll
        for (int w = 0; w < NWG; ++w) {
            int v = p[(size_t)w * N];
            p[(size_t)w * N] = (unsigned short)sum;   // exclusive prefix (rank base per chunk)
            sum += v;
        }
        float r = rsqrtf((float)max(sum, 1));
        if (g < 5) { cnt_dst[i] = sum; rsq_in[i] = r; }
        else rsq_out[i - 5 * N] = r;
    }
}

// 5 blocks, one per etype
__global__ __launch_bounds__(1024) void scan_kernel(const int* __restrict__ cnt_all,
                                                    int* __restrict__ off_all, int n) {
    const int* cnt = cnt_all + (size_t)blockIdx.x * n;
    int* off = off_all + (size_t)blockIdx.x * (n + 1);
    __shared__ int ssum[1024];
    int t = threadIdx.x;
    int chunk = (n + 1023) / 1024;
    int lo = t * chunk, hi = min(lo + chunk, n);
    int s = 0;
    for (int i = lo; i < hi; ++i) s += cnt[i];
    ssum[t] = s;
    __syncthreads();
    for (int d = 1; d < 1024; d <<= 1) {
        int v = (t >= d) ? ssum[t - d] : 0;
        __syncthreads();
        ssum[t] += v;
        __syncthreads();
    }
    int excl = (t == 0) ? 0 : ssum[t - 1];
    for (int i = lo; i < hi; ++i) { off[i] = excl; excl += cnt[i]; }
    if (t == 1023) off[n] = ssum[1023];
}

// ---------------- atomic-free permutation: sorted_src (ushort) grouped by dst ----------------
__global__ void permute_kernel(const int* __restrict__ src_all, const int* __restrict__ dst_all,
                               const int* __restrict__ off, const unsigned short* __restrict__ partial,
                               const unsigned short* __restrict__ rank_local,
                               unsigned short* __restrict__ sorted, int E, int N) {
    int i = blockIdx.x * blockDim.x + threadIdx.x;
    int stride = gridDim.x * blockDim.x;
    int tot = 5 * E;
    int C = (E + NWG - 1) / NWG;
    for (; i < tot; i += stride) {
        int k = i / E, e = i - k * E;
        int w = e / C;
        int d = __builtin_nontemporal_load(&dst_all[i]);
        int s = __builtin_nontemporal_load(&src_all[i]);
        int rl = __builtin_nontemporal_load(&rank_local[i]);
        int pos = off[(size_t)k * (N + 1) + d]
                + partial[((size_t)k * NWG + w) * N + d]
                + rl;
        __builtin_nontemporal_store((unsigned short)s, &sorted[(size_t)k * E + pos]);
    }
}

// ---------------- feat: f32 [N][385] -> bf16 [N][384] + alast [N] (col 384) ----------------
__global__ void convert_kernel(const float* __restrict__ f0, const float* __restrict__ f1,
                               const float* __restrict__ f2, const float* __restrict__ f3,
                               unsigned int* __restrict__ featB,   // [4][N][192] uints
                               float* __restrict__ alast, int N) {
    int i = blockIdx.x * blockDim.x + threadIdx.x;
    int stride = gridDim.x * blockDim.x;
    int per = N * 192;
    int tot = 4 * per;
    for (int p = i; p < tot; p += stride) {
        int t = p / per, rem = p - t * per;
        int n = rem / 192, c2 = (rem - n * 192) * 2;
        const float* f = (t < 2) ? (t == 0 ? f0 : f1) : (t == 2 ? f2 : f3);
        const float* row = f + (size_t)n * INF;
        float a = row[c2], b = row[c2 + 1];
        featB[p] = ((unsigned int)f2b(b) << 16) | f2b(a);
    }
    for (int p = i; p < 4 * N; p += stride) {
        int t = p / N, n = p - t * N;
        const float* f = (t < 2) ? (t == 0 ? f0 : f1) : (t == 2 ? f2 : f3);
        alast[p] = f[(size_t)n * INF + 384];
    }
}

// ---------------- weight prep: transpose + bf16, combined biases ----------------
__global__ void prep_weights_kernel(const float* __restrict__ Wp,
                                    const float* __restrict__ Wc1, const float* __restrict__ Wc2,
                                    const float* __restrict__ bc1, const float* __restrict__ bc2,
                                    unsigned short* __restrict__ WpT,
                                    unsigned short* __restrict__ WcT,
                                    float* __restrict__ cbias) {
    int i = blockIdx.x * blockDim.x + threadIdx.x;
    int stride = gridDim.x * blockDim.x;
    const int nWp = 4 * 128 * 384;
    for (int p = i; p < nWp; p += stride) {
        int t = p / (128 * 384), rem = p % (128 * 384);
        int c = rem / 384, k = rem % 384;
        WpT[p] = f2b(Wp[(size_t)t * INF * HD + (size_t)k * HD + c]);
    }
    const int nWc = 5 * 128 * 128;
    for (int p = i; p < 2 * nWc; p += stride) {
        int layer = p / nWc, rem = p % nWc;
        int e = rem / (128 * 128), rem2 = rem % (128 * 128);
        int c = rem2 / 128, k = rem2 % 128;
        const float* W = layer ? Wc2 : Wc1;
        WcT[p] = f2b(W[(size_t)e * 128 * 128 + (size_t)k * 128 + c]);
    }
    // cbias[layer][t][c]: t0<-bc[4], t1<-bc[0], t2<-bc[2]+bc[3], t3<-bc[1]
    for (int p = i; p < 2 * 4 * 128; p += stride) {
        int layer = p / 512, rem = p % 512;
        int t = rem / 128, c = rem % 128;
        const float* bc = layer ? bc2 : bc1;
        float v;
        if (t == 0) v = bc[4 * 128 + c];
        else if (t == 1) v = bc[0 * 128 + c];
        else if (t == 2) v = bc[2 * 128 + c] + bc[3 * 128 + c];
        else v = bc[1 * 128 + c];
        cbias[p] = v;
    }
}

// ---------------- batched MFMA GEMM (bf16 A), optional rank-1 / bias / rowscale ----------------
struct GemmDesc {
    const unsigned short* A;      // [M][lda] bf16, rows 16B-aligned
    const unsigned short* Bt;     // [128][K] bf16
    const float* bias;            // [128] or null
    const float* rowscale;        // [M] or null
    const float* alast;           // [M] or null (rank-1 left vector)
    const float* wlast;           // [128] or null (rank-1 right vector)
    unsigned short* out;          // [M][128] bf16
};
struct GemmBatch { GemmDesc d[5]; };

__global__ __launch_bounds__(256) void gemm_mfma_kernel(
    GemmBatch batch, int lda, int M, int K, int relu)
{
    const GemmDesc dsc = batch.d[blockIdx.y];
    const unsigned short* __restrict__ Bt = dsc.Bt;
    const unsigned short* __restrict__ A = dsc.A;

    __shared__ __align__(16) unsigned short As[64][72];   // +8 pad: 144B row stride
    __shared__ __align__(16) unsigned short Bs[128][72];
    const int tid = threadIdx.x;
    const int bm = blockIdx.x * 64;
    const int wid = tid >> 6, lane = tid & 63;
    const int wr = wid & 1, wc = wid >> 1;      // 2x2 wave grid: 32 rows x 64 cols each
    const int l15 = lane & 15, l4 = lane >> 4;

    f32x4 acc[2][4] = {};

    for (int k0 = 0; k0 < K; k0 += 64) {
        {
            int r = tid >> 2, q = tid & 3;      // 16 bf16 per thread, vectorized
            int gm = bm + r;
            if (gm < M) {
                const uint4* g = (const uint4*)(A + (size_t)gm * lda + k0 + q * 16);
                *(uint4*)&As[r][q * 16] = g[0];
                *(uint4*)&As[r][q * 16 + 8] = g[1];
            } else {
                uint4 z = {0, 0, 0, 0};
                *(uint4*)&As[r][q * 16] = z;
                *(uint4*)&As[r][q * 16 + 8] = z;
            }
        }
        {
            int col = tid >> 1, hf = tid & 1;   // 32 bf16 per thread from Bt[col][k0+hf*32..]
            const uint4* g = (const uint4*)(Bt + (size_t)col * K + k0 + hf * 32);
            #pragma unroll
            for (int j = 0; j < 4; ++j)
                *(uint4*)&Bs[col][hf * 32 + j * 8] = g[j];
        }
        __syncthreads();
        #pragma unroll
        for (int kk = 0; kk < 2; ++kk) {
            short8 a[2], b[4];
            #pragma unroll
            for (int mi = 0; mi < 2; ++mi)
                a[mi] = *(const short8*)&As[wr * 32 + mi * 16 + l15][kk * 32 + l4 * 8];
            #pragma unroll
            for (int ni = 0; ni < 4; ++ni)
                b[ni] = *(const short8*)&Bs[wc * 64 + ni * 16 + l15][kk * 32 + l4 * 8];
            #pragma unroll
            for (int mi = 0; mi < 2; ++mi)
                #pragma unroll
                for (int ni = 0; ni < 4; ++ni)
                    acc[mi][ni] = __builtin_amdgcn_mfma_f32_16x16x32_bf16(
                        a[mi], b[ni], acc[mi][ni], 0, 0, 0);
        }
        __syncthreads();
    }

    // epilogue: C/D layout col=lane&15, row=(lane>>4)*4+reg  [m89-verified]
    #pragma unroll
    for (int mi = 0; mi < 2; ++mi) {
        #pragma unroll
        for (int r = 0; r < 4; ++r) {
            int grow = bm + wr * 32 + mi * 16 + l4 * 4 + r;
            if (grow >= M) continue;
            float rs = dsc.rowscale ? dsc.rowscale[grow] : 1.f;
            float al = dsc.alast ? dsc.alast[grow] : 0.f;
            #pragma unroll
            for (int ni = 0; ni < 4; ++ni) {
                int gcol = wc * 64 + ni * 16 + l15;
                float v = acc[mi][ni][r];
                if (dsc.wlast) v += al * dsc.wlast[gcol];
                if (dsc.bias) v += dsc.bias[gcol];
                v *= rs;
                if (relu) v = fmaxf(v, 0.f);
                dsc.out[(size_t)grow * HD + gcol] = f2b(v);
            }
        }
    }
}

// ---------------- batched CSR gather: one wave per node, fp32 accum, fused bias+relu ----------------
struct GatherDesc {
    const unsigned short* msgA; const unsigned short* sortedA;
    const int* offA; const float* rsqA;
    const unsigned short* msgB; const unsigned short* sortedB;  // null if single
    const int* offB; const float* rsqB;
    const float* bias; void* out;
};
struct GatherBatch { GatherDesc d[4]; };

template<int OUT_BF16>
__global__ __launch_bounds__(256) void gather_kernel(GatherBatch batch, int n)
{
    const GatherDesc d = batch.d[blockIdx.y];
    int node = blockIdx.x * 4 + (threadIdx.x >> 6);
    if (node >= n) return;
    int lane = threadIdx.x & 63;

    float ox, oy;
    {
        float ax = 0.f, ay = 0.f;
        int beg = d.offA[node], end = d.offA[node + 1];
        int e = beg;
        for (; e + 3 < end; e += 4) {
            int s0 = d.sortedA[e], s1 = d.sortedA[e + 1];
            int s2 = d.sortedA[e + 2], s3 = d.sortedA[e + 3];
            unsigned int v0 = *(const unsigned int*)(d.msgA + (size_t)s0 * HD + lane * 2);
            unsigned int v1 = *(const unsigned int*)(d.msgA + (size_t)s1 * HD + lane * 2);
            unsigned int v2 = *(const unsigned int*)(d.msgA + (size_t)s2 * HD + lane * 2);
            unsigned int v3 = *(const unsigned int*)(d.msgA + (size_t)s3 * HD + lane * 2);
            ax += b2f(v0 & 0xffffu) + b2f(v1 & 0xffffu) + b2f(v2 & 0xffffu) + b2f(v3 & 0xffffu);
            ay += b2f(v0 >> 16) + b2f(v1 >> 16) + b2f(v2 >> 16) + b2f(v3 >> 16);
        }
        for (; e < end; ++e) {
            int s0 = d.sortedA[e];
            unsigned int v0 = *(const unsigned int*)(d.msgA + (size_t)s0 * HD + lane * 2);
            ax += b2f(v0 & 0xffffu);
            ay += b2f(v0 >> 16);
        }
        float r = d.rsqA[node];
        ox = ax * r; oy = ay * r;
    }
    if (d.msgB) {
        float bx = 0.f, by = 0.f;
        int beg = d.offB[node], end = d.offB[node + 1];
        int e = beg;
        for (; e + 3 < end; e += 4) {
            int s0 = d.sortedB[e], s1 = d.sortedB[e + 1];
            int s2 = d.sortedB[e + 2], s3 = d.sortedB[e + 3];
            unsigned int v0 = *(const unsigned int*)(d.msgB + (size_t)s0 * HD + lane * 2);
            unsigned int v1 = *(const unsigned int*)(d.msgB + (size_t)s1 * HD + lane * 2);
            unsigned int v2 = *(const unsigned int*)(d.msgB + (size_t)s2 * HD + lane * 2);
            unsigned int v3 = *(const unsigned int*)(d.msgB + (size_t)s3 * HD + lane * 2);
            bx += b2f(v0 & 0xffffu) + b2f(v1 & 0xffffu) + b2f(v2 & 0xffffu) + b2f(v3 & 0xffffu);
            by += b2f(v0 >> 16) + b2f(v1 >> 16) + b2f(v2 >> 16) + b2f(v3 >> 16);
        }
        for (; e < end; ++e) {
            int s0 = d.sortedB[e];
            unsigned int v0 = *(const unsigned int*)(d.msgB + (size_t)s0 * HD + lane * 2);
            bx += b2f(v0 & 0xffffu);
            by += b2f(v0 >> 16);
        }
        float r = d.rsqB[node];
        ox += bx * r; oy += by * r;
    }
    float2 bv = *(const float2*)(d.bias + lane * 2);
    ox = fmaxf(ox + bv.x, 0.f);
    oy = fmaxf(oy + bv.y, 0.f);
    if (OUT_BF16) {
        unsigned int packed = ((unsigned int)f2b(oy) << 16) | f2b(ox);
        ((unsigned int*)d.out)[(size_t)node * (HD / 2) + lane] = packed;
    } else {
        float2 o = {ox, oy};
        ((float2*)d.out)[(size_t)node * (HD / 2) + lane] = o;
    }
}

extern "C" void kernel_launch(void* const* d_in, const int* in_sizes, int n_in,
                              void* d_out, int out_size, void* d_ws, size_t ws_size,
                              hipStream_t stream)
{
    const float* feat[4] = {(const float*)d_in[0], (const float*)d_in[1],
                            (const float*)d_in[2], (const float*)d_in[3]};
    const int* src_all = (const int*)d_in[4];
    const int* dst_all = (const int*)d_in[5];
    const float* Wp  = (const float*)d_in[6];
    const float* bp  = (const float*)d_in[7];
    const float* Wc1 = (const float*)d_in[8];
    const float* bc1 = (const float*)d_in[9];
    const float* Wc2 = (const float*)d_in[10];
    const float* bc2 = (const float*)d_in[11];

    const int N = in_sizes[0] / INF;      // 50000  (< 65536: ushort ids)
    const int E = in_sizes[4] / 5;        // 1,600,000

    // etypes: k -> (src_type, dst_type): (0,1) (1,3) (3,2) (0,2) (2,0)
    const int st_[5] = {0, 1, 3, 0, 2};

    // ---- workspace layout (256B-aligned); overlay region for lifetime-disjoint buffers ----
    char* w = (char*)d_ws;
    auto take = [&](size_t bytes) { char* p = w; w += (bytes + 255) & ~(size_t)255; return p; };
    int*   cnt_dst = (int*)take(5 * (size_t)N * 4);
    float* rsq_out = (float*)take(5 * (size_t)N * 4);
    float* rsq_in  = (float*)take(5 * (size_t)N * 4);
    int*   off     = (int*)take(5 * (size_t)(N + 1) * 4);
    unsigned short* sorted = (unsigned short*)take(5 * (size_t)E * 2);  // 16 MB, live whole pass
    float* alast   = (float*)take(4 * (size_t)N * 4);
    unsigned short* WpT = (unsigned short*)take(4 * 128 * 384 * 2);
    unsigned short* WcT = (unsigned short*)take(2 * 5 * 128 * 128 * 2);
    float* cbias   = (float*)take(2 * 4 * 128 * 4);
    // overlay blob:
    //   phase A (CSR build): partial [10][NWG][N] u16 (16MB) + rank_local [5][E] u16 (16MB)
    //   phase B (convert+proj): featB [4][N][384] bf16 (153.6MB) -- clobbers A after permute
    //   phase C (conv layers): msg[5] (64MB) at blob+32MB -- clobbers featB after proj
    size_t blob_sz = 4 * (size_t)N * 384 * 2;                 // 153.6 MB dominates
    char* blob = (char*)take(blob_sz);
    unsigned short* partial    = (unsigned short*)blob;                      // 16 MB
    unsigned short* rank_local = (unsigned short*)(blob + 10u * NWG * (size_t)N * 2);
    unsigned short* featB      = (unsigned short*)blob;
    unsigned short* msg        = (unsigned short*)(blob + 32u * 1024 * 1024);
    // h0 in d_out lower half (bf16), h1 in d_out upper half (bf16); both dead
    // before layer-2 gathers write f32 over the full d_out.
    unsigned short* h0 = (unsigned short*)d_out;
    unsigned short* h1 = (unsigned short*)d_out + 4 * (size_t)N * HD;

    // ---- prep: weights + CSR (no device-scope atomics anywhere) ----
    prep_weights_kernel<<<512, 256, 0, stream>>>(Wp, Wc1, Wc2, bc1, bc2, WpT, WcT, cbias);
    hist_kernel<<<10 * NWG, 1024, 0, stream>>>(src_all, dst_all, partial, rank_local, E, N);
    reduce_kernel<<<(10 * N + 255) / 256, 256, 0, stream>>>(partial, cnt_dst, rsq_out, rsq_in, N);
    scan_kernel<<<5, 1024, 0, stream>>>(cnt_dst, off, N);
    permute_kernel<<<2048, 256, 0, stream>>>(src_all, dst_all, off, partial, rank_local,
                                             sorted, E, N);

    // ---- feat f32 -> featB bf16 [N][384] + alast ----
    convert_kernel<<<2048, 256, 0, stream>>>(feat[0], feat[1], feat[2], feat[3],
                                             (unsigned int*)featB, alast, N);

    const int gblk = (N + 63) / 64;

    // ---- input projections (batched over 4 types) ----
    {
        GemmBatch pb = {};
        for (int t = 0; t < 4; ++t) {
            pb.d[t].A = featB + (size_t)t * N * 384;
            pb.d[t].Bt = WpT + (size_t)t * 128 * 384;
            pb.d[t].bias = bp + (size_t)t * HD;
            pb.d[t].rowscale = nullptr;
            pb.d[t].alast = alast + (size_t)t * N;
            pb.d[t].wlast = Wp + (size_t)t * INF * HD + 384 * HD;
            pb.d[t].out = h0 + (size_t)t * N * HD;
        }
        gemm_mfma_kernel<<<dim3(gblk, 4), 256, 0, stream>>>(pb, 384, N, 384, 1);
    }

    // ---- 2 hetero conv layers ----
    for (int layer = 0; layer < 2; ++layer) {
        const unsigned short* hin = layer ? h1 : h0;
        const unsigned short* WT = WcT + (size_t)layer * 5 * 128 * 128;
        const float* cb = cbias + (size_t)layer * 4 * 128;

        // 5 independent conv GEMMs in one dispatch
        {
            GemmBatch cbch = {};
            for (int k = 0; k < 5; ++k) {
                cbch.d[k].A = hin + (size_t)st_[k] * N * HD;
                cbch.d[k].Bt = WT + (size_t)k * 128 * 128;
                cbch.d[k].bias = nullptr;
                cbch.d[k].rowscale = rsq_out + (size_t)k * N;
                cbch.d[k].alast = nullptr;
                cbch.d[k].wlast = nullptr;
                cbch.d[k].out = msg + (size_t)k * N * HD;
            }
            gemm_mfma_kernel<<<dim3(gblk, 5), 256, 0, stream>>>(cbch, HD, N, 128, 0);
        }

        // 4 gathers (k2+k3 dual into t2) in one dispatch
        {
            auto S = [&](int k) { return sorted + (size_t)k * E; };
            auto O = [&](int k) { return off + (size_t)k * (N + 1); };
            auto R = [&](int k) { return rsq_in + (size_t)k * N; };
            auto M_ = [&](int k) { return msg + (size_t)k * N * HD; };
            // dst ntype per y: y0->t1(k0), y1->t3(k1), y2->t2(k2+k3), y3->t0(k4)
            const int ksA[4] = {0, 1, 2, 4};
            const int dt [4] = {1, 3, 2, 0};
            GatherBatch gb = {};
            for (int y = 0; y < 4; ++y) {
                int k = ksA[y];
                gb.d[y].msgA = M_(k); gb.d[y].sortedA = S(k);
                gb.d[y].offA = O(k);  gb.d[y].rsqA = R(k);
                gb.d[y].msgB = nullptr; gb.d[y].sortedB = nullptr;
                gb.d[y].offB = nullptr; gb.d[y].rsqB = nullptr;
                gb.d[y].bias = cb + (size_t)dt[y] * HD;
                if (layer == 0)
                    gb.d[y].out = h1 + (size_t)dt[y] * N * HD;
                else
                    gb.d[y].out = (float*)d_out + (size_t)dt[y] * N * HD;
            }
            gb.d[2].msgB = M_(3); gb.d[2].sortedB = S(3);
            gb.d[2].offB = O(3);  gb.d[2].rsqB = R(3);
            const int gg = (N + 3) / 4;
            if (layer == 0)
                gather_kernel<1><<<dim3(gg, 4), 256, 0, stream>>>(gb, N);
            else
                gather_kernel<0><<<dim3(gg, 4), 256, 0, stream>>>(gb, N);
        }
    }
}

// Round 8
// 1146.283 us; speedup vs baseline: 25.2849x; 1.0397x over previous
//
#include <hip/hip_runtime.h>
#include <hip/hip_bf16.h>

#define INF 385
#define HD 128
#define NWG 16   // workgroups per histogram group
#define HIST_BLOCKS (10 * NWG)

typedef __attribute__((ext_vector_type(8))) short short8;
typedef __attribute__((ext_vector_type(4))) float f32x4;

__device__ inline unsigned short f2b(float f) {
    __hip_bfloat16 h = __float2bfloat16(f);
    return *reinterpret_cast<unsigned short*>(&h);
}
__device__ inline float b2f(unsigned int lo16) {
    union { unsigned int u; float f; } c; c.u = lo16 << 16; return c.f;
}

// ---------------- convert body: feat f32 [N][385] -> bf16 [N][384] + alast ----------------
__device__ __forceinline__ void convert_body(
    const float* f0, const float* f1, const float* f2, const float* f3,
    unsigned int* featB, float* alast, int N, int gid, int nthr)
{
    int per = N * 192;
    int tot = 4 * per;
    for (int p = gid; p < tot; p += nthr) {
        int t = p / per, rem = p - t * per;
        int n = rem / 192, c2 = (rem - n * 192) * 2;
        const float* f = (t < 2) ? (t == 0 ? f0 : f1) : (t == 2 ? f2 : f3);
        const float* row = f + (size_t)n * INF;
        float a = row[c2], b = row[c2 + 1];
        featB[p] = ((unsigned int)f2b(b) << 16) | f2b(a);
    }
    for (int p = gid; p < 4 * N; p += nthr) {
        int t = p / N, n = p - t * N;
        const float* f = (t < 2) ? (t == 0 ? f0 : f1) : (t == 2 ? f2 : f3);
        alast[p] = f[(size_t)n * INF + 384];
    }
}

// ---------------- fused: LDS-privatized histogram (blocks<HIST_BLOCKS) + convert ----------------
__global__ __launch_bounds__(1024) void hist_conv_kernel(
    const int* __restrict__ src_all, const int* __restrict__ dst_all,
    unsigned short* __restrict__ partial,    // [10][NWG][N]
    unsigned short* __restrict__ rank_local, // [5][E]
    int E, int N,
    const float* __restrict__ f0, const float* __restrict__ f1,
    const float* __restrict__ f2, const float* __restrict__ f3,
    unsigned int* __restrict__ featB, float* __restrict__ alast)
{
    __shared__ unsigned int cnt[25000];      // 2 packed ushort counters per uint
    int tid = threadIdx.x;
    if (blockIdx.x >= HIST_BLOCKS) {
        int nconv = gridDim.x - HIST_BLOCKS;
        convert_body(f0, f1, f2, f3, featB, alast, N,
                     (blockIdx.x - HIST_BLOCKS) * 1024 + tid, nconv * 1024);
        return;
    }
    int g = blockIdx.x / NWG;
    int w = blockIdx.x % NWG;
    int half = (N + 1) / 2;
    for (int i = tid; i < half; i += 1024) cnt[i] = 0;
    __syncthreads();

    int C = (E + NWG - 1) / NWG;
    int lo = w * C, hi = min(lo + C, E);
    if (g < 5) {
        const int* arr = dst_all + (size_t)g * E;
        for (int e = lo + tid; e < hi; e += 1024) {
            int d = __builtin_nontemporal_load(&arr[e]);
            unsigned int sh = (d & 1) * 16;
            unsigned int old = atomicAdd(&cnt[d >> 1], 1u << sh);
            rank_local[(size_t)g * E + e] = (unsigned short)((old >> sh) & 0xffffu);
        }
    } else {
        const int* arr = src_all + (size_t)(g - 5) * E;
        for (int e = lo + tid; e < hi; e += 1024) {
            int d = __builtin_nontemporal_load(&arr[e]);
            atomicAdd(&cnt[d >> 1], 1u << ((d & 1) * 16));
        }
    }
    __syncthreads();
    unsigned short* outp = partial + ((size_t)g * NWG + w) * N;
    for (int n = tid; n < N; n += 1024)
        outp[n] = (unsigned short)((cnt[n >> 1] >> ((n & 1) * 16)) & 0xffffu);
}

// ---------------- reduce partials -> degrees/rsqrt; in-place exclusive prefix over chunks ----------------
__global__ void reduce_kernel(unsigned short* __restrict__ partial, int* __restrict__ cnt_dst,
                              float* __restrict__ rsq_out, float* __restrict__ rsq_in, int N) {
    int i = blockIdx.x * blockDim.x + threadIdx.x;
    int stride = gridDim.x * blockDim.x;
    int tot = 10 * N;
    for (; i < tot; i += stride) {
        int g = i / N, n = i - g * N;
        unsigned short* p = partial + ((size_t)g * NWG) * N + n;
        int sum = 0;
        #pragma unroll
        for (int w = 0; w < NWG; ++w) {
            int v = p[(size_t)w * N];
            p[(size_t)w * N] = (unsigned short)sum;   // exclusive prefix (rank base per chunk)
            sum += v;
        }
        float r = rsqrtf((float)max(sum, 1));
        if (g < 5) { cnt_dst[i] = sum; rsq_in[i] = r; }
        else rsq_out[i - 5 * N] = r;
    }
}

// 5 blocks, one per etype
__global__ __launch_bounds__(1024) void scan_kernel(const int* __restrict__ cnt_all,
                                                    int* __restrict__ off_all, int n) {
    const int* cnt = cnt_all + (size_t)blockIdx.x * n;
    int* off = off_all + (size_t)blockIdx.x * (n + 1);
    __shared__ int ssum[1024];
    int t = threadIdx.x;
    int chunk = (n + 1023) / 1024;
    int lo = t * chunk, hi = min(lo + chunk, n);
    int s = 0;
    for (int i = lo; i < hi; ++i) s += cnt[i];
    ssum[t] = s;
    __syncthreads();
    for (int d = 1; d < 1024; d <<= 1) {
        int v = (t >= d) ? ssum[t - d] : 0;
        __syncthreads();
        ssum[t] += v;
        __syncthreads();
    }
    int excl = (t == 0) ? 0 : ssum[t - 1];
    for (int i = lo; i < hi; ++i) { off[i] = excl; excl += cnt[i]; }
    if (t == 1023) off[n] = ssum[1023];
}

// ---------------- atomic-free permutation body ----------------
__device__ __forceinline__ void permute_body(
    const int* __restrict__ src_all, const int* __restrict__ dst_all,
    const int* __restrict__ off, const unsigned short* __restrict__ partial,
    const unsigned short* __restrict__ rank_local,
    unsigned short* __restrict__ sorted, int E, int N, int gid, int nthr)
{
    int tot = 5 * E;
    int C = (E + NWG - 1) / NWG;
    for (int i = gid; i < tot; i += nthr) {
        int k = i / E, e = i - k * E;
        int w = e / C;
        int d = __builtin_nontemporal_load(&dst_all[i]);
        int s = __builtin_nontemporal_load(&src_all[i]);
        int rl = __builtin_nontemporal_load(&rank_local[i]);
        int pos = off[(size_t)k * (N + 1) + d]
                + partial[((size_t)k * NWG + w) * N + d]
                + rl;
        __builtin_nontemporal_store((unsigned short)s, &sorted[(size_t)k * E + pos]);
    }
}

__global__ void permute_kernel(const int* __restrict__ src_all, const int* __restrict__ dst_all,
                               const int* __restrict__ off, const unsigned short* __restrict__ partial,
                               const unsigned short* __restrict__ rank_local,
                               unsigned short* __restrict__ sorted, int E, int N) {
    permute_body(src_all, dst_all, off, partial, rank_local, sorted, E, N,
                 blockIdx.x * blockDim.x + threadIdx.x, gridDim.x * blockDim.x);
}

// ---------------- feat convert (standalone, fallback path) ----------------
__global__ void convert_kernel(const float* __restrict__ f0, const float* __restrict__ f1,
                               const float* __restrict__ f2, const float* __restrict__ f3,
                               unsigned int* __restrict__ featB, float* __restrict__ alast, int N) {
    convert_body(f0, f1, f2, f3, featB, alast, N,
                 blockIdx.x * blockDim.x + threadIdx.x, gridDim.x * blockDim.x);
}

// ---------------- weight prep: transpose + bf16, combined biases ----------------
__global__ void prep_weights_kernel(const float* __restrict__ Wp,
                                    const float* __restrict__ Wc1, const float* __restrict__ Wc2,
                                    const float* __restrict__ bc1, const float* __restrict__ bc2,
                                    unsigned short* __restrict__ WpT,
                                    unsigned short* __restrict__ WcT,
                                    float* __restrict__ cbias) {
    int i = blockIdx.x * blockDim.x + threadIdx.x;
    int stride = gridDim.x * blockDim.x;
    const int nWp = 4 * 128 * 384;
    for (int p = i; p < nWp; p += stride) {
        int t = p / (128 * 384), rem = p % (128 * 384);
        int c = rem / 384, k = rem % 384;
        WpT[p] = f2b(Wp[(size_t)t * INF * HD + (size_t)k * HD + c]);
    }
    const int nWc = 5 * 128 * 128;
    for (int p = i; p < 2 * nWc; p += stride) {
        int layer = p / nWc, rem = p % nWc;
        int e = rem / (128 * 128), rem2 = rem % (128 * 128);
        int c = rem2 / 128, k = rem2 % 128;
        const float* W = layer ? Wc2 : Wc1;
        WcT[p] = f2b(W[(size_t)e * 128 * 128 + (size_t)k * 128 + c]);
    }
    // cbias[layer][t][c]: t0<-bc[4], t1<-bc[0], t2<-bc[2]+bc[3], t3<-bc[1]
    for (int p = i; p < 2 * 4 * 128; p += stride) {
        int layer = p / 512, rem = p % 512;
        int t = rem / 128, c = rem % 128;
        const float* bc = layer ? bc2 : bc1;
        float v;
        if (t == 0) v = bc[4 * 128 + c];
        else if (t == 1) v = bc[0 * 128 + c];
        else if (t == 2) v = bc[2 * 128 + c] + bc[3 * 128 + c];
        else v = bc[1 * 128 + c];
        cbias[p] = v;
    }
}

// ---------------- MFMA GEMM tile (device body) ----------------
struct GemmDesc {
    const unsigned short* A;      // [M][lda] bf16, rows 16B-aligned
    const unsigned short* Bt;     // [128][K] bf16
    const float* bias;            // [128] or null
    const float* rowscale;        // [M] or null
    const float* alast;           // [M] or null (rank-1 left vector)
    const float* wlast;           // [128] or null (rank-1 right vector)
    unsigned short* out;          // [M][128] bf16
};
struct GemmBatch { GemmDesc d[5]; };

__device__ __forceinline__ void gemm_tile(
    const GemmDesc& dsc, int lda, int M, int K, int relu,
    unsigned short (*As)[72], unsigned short (*Bs)[72])
{
    const unsigned short* __restrict__ Bt = dsc.Bt;
    const unsigned short* __restrict__ A = dsc.A;
    const int tid = threadIdx.x;
    const int bm = blockIdx.x * 64;
    const int wid = tid >> 6, lane = tid & 63;
    const int wr = wid & 1, wc = wid >> 1;      // 2x2 wave grid: 32 rows x 64 cols each
    const int l15 = lane & 15, l4 = lane >> 4;

    f32x4 acc[2][4] = {};

    for (int k0 = 0; k0 < K; k0 += 64) {
        {
            int r = tid >> 2, q = tid & 3;      // 16 bf16 per thread, vectorized
            int gm = bm + r;
            if (gm < M) {
                const uint4* g = (const uint4*)(A + (size_t)gm * lda + k0 + q * 16);
                *(uint4*)&As[r][q * 16] = g[0];
                *(uint4*)&As[r][q * 16 + 8] = g[1];
            } else {
                uint4 z = {0, 0, 0, 0};
                *(uint4*)&As[r][q * 16] = z;
                *(uint4*)&As[r][q * 16 + 8] = z;
            }
        }
        {
            int col = tid >> 1, hf = tid & 1;   // 32 bf16 per thread from Bt[col][k0+hf*32..]
            const uint4* g = (const uint4*)(Bt + (size_t)col * K + k0 + hf * 32);
            #pragma unroll
            for (int j = 0; j < 4; ++j)
                *(uint4*)&Bs[col][hf * 32 + j * 8] = g[j];
        }
        __syncthreads();
        #pragma unroll
        for (int kk = 0; kk < 2; ++kk) {
            short8 a[2], b[4];
            #pragma unroll
            for (int mi = 0; mi < 2; ++mi)
                a[mi] = *(const short8*)&As[wr * 32 + mi * 16 + l15][kk * 32 + l4 * 8];
            #pragma unroll
            for (int ni = 0; ni < 4; ++ni)
                b[ni] = *(const short8*)&Bs[wc * 64 + ni * 16 + l15][kk * 32 + l4 * 8];
            #pragma unroll
            for (int mi = 0; mi < 2; ++mi)
                #pragma unroll
                for (int ni = 0; ni < 4; ++ni)
                    acc[mi][ni] = __builtin_amdgcn_mfma_f32_16x16x32_bf16(
                        a[mi], b[ni], acc[mi][ni], 0, 0, 0);
        }
        __syncthreads();
    }

    // epilogue: C/D layout col=lane&15, row=(lane>>4)*4+reg  [m89-verified]
    #pragma unroll
    for (int mi = 0; mi < 2; ++mi) {
        #pragma unroll
        for (int r = 0; r < 4; ++r) {
            int grow = bm + wr * 32 + mi * 16 + l4 * 4 + r;
            if (grow >= M) continue;
            float rs = dsc.rowscale ? dsc.rowscale[grow] : 1.f;
            float al = dsc.alast ? dsc.alast[grow] : 0.f;
            #pragma unroll
            for (int ni = 0; ni < 4; ++ni) {
                int gcol = wc * 64 + ni * 16 + l15;
                float v = acc[mi][ni][r];
                if (dsc.wlast) v += al * dsc.wlast[gcol];
                if (dsc.bias) v += dsc.bias[gcol];
                v *= rs;
                if (relu) v = fmaxf(v, 0.f);
                dsc.out[(size_t)grow * HD + gcol] = f2b(v);
            }
        }
    }
}

__global__ __launch_bounds__(256) void gemm_mfma_kernel(
    GemmBatch batch, int lda, int M, int K, int relu)
{
    __shared__ __align__(16) unsigned short As[64][72];
    __shared__ __align__(16) unsigned short Bs[128][72];
    gemm_tile(batch.d[blockIdx.y], lda, M, K, relu, As, Bs);
}

// ---------------- fused: proj GEMM (y<4) + permute (y==4) ----------------
__global__ __launch_bounds__(256) void permute_proj_kernel(
    GemmBatch batch, int lda, int M, int K, int relu, int gblk,
    const int* __restrict__ src_all, const int* __restrict__ dst_all,
    const int* __restrict__ off, const unsigned short* __restrict__ partial,
    const unsigned short* __restrict__ rank_local,
    unsigned short* __restrict__ sorted, int E, int N)
{
    if (blockIdx.y == 4) {
        permute_body(src_all, dst_all, off, partial, rank_local, sorted, E, N,
                     blockIdx.x * 256 + threadIdx.x, gridDim.x * 256);
        return;
    }
    if ((int)blockIdx.x >= gblk) return;
    __shared__ __align__(16) unsigned short As[64][72];
    __shared__ __align__(16) unsigned short Bs[128][72];
    gemm_tile(batch.d[blockIdx.y], lda, M, K, relu, As, Bs);
}

// ---------------- batched CSR gather: one wave per node, 8-edge unroll, fused bias+relu ----------------
struct GatherDesc {
    const unsigned short* msgA; const unsigned short* sortedA;
    const int* offA; const float* rsqA;
    const unsigned short* msgB; const unsigned short* sortedB;  // null if single
    const int* offB; const float* rsqB;
    const float* bias; void* out;
};
struct GatherBatch { GatherDesc d[4]; };

template<int OUT_BF16>
__global__ __launch_bounds__(256) void gather_kernel(GatherBatch batch, int n)
{
    const GatherDesc d = batch.d[blockIdx.y];
    int node = blockIdx.x * 4 + (threadIdx.x >> 6);
    if (node >= n) return;
    int lane = threadIdx.x & 63;
    const size_t loff = (size_t)lane * 2;

    float ox, oy;
    {
        float ax = 0.f, ay = 0.f;
        int beg = d.offA[node], end = d.offA[node + 1];
        int e = beg;
        for (; e + 8 <= end; e += 8) {
            int s[8];
            unsigned int v[8];
            #pragma unroll
            for (int j = 0; j < 8; ++j) s[j] = d.sortedA[e + j];
            #pragma unroll
            for (int j = 0; j < 8; ++j)
                v[j] = *(const unsigned int*)(d.msgA + (size_t)s[j] * HD + loff);
            #pragma unroll
            for (int j = 0; j < 8; ++j) {
                ax += b2f(v[j] & 0xffffu);
                ay += b2f(v[j] >> 16);
            }
        }
        for (; e < end; ++e) {
            int s0 = d.sortedA[e];
            unsigned int v0 = *(const unsigned int*)(d.msgA + (size_t)s0 * HD + loff);
            ax += b2f(v0 & 0xffffu);
            ay += b2f(v0 >> 16);
        }
        float r = d.rsqA[node];
        ox = ax * r; oy = ay * r;
    }
    if (d.msgB) {
        float bx = 0.f, by = 0.f;
        int beg = d.offB[node], end = d.offB[node + 1];
        int e = beg;
        for (; e + 8 <= end; e += 8) {
            int s[8];
            unsigned int v[8];
            #pragma unroll
            for (int j = 0; j < 8; ++j) s[j] = d.sortedB[e + j];
            #pragma unroll
            for (int j = 0; j < 8; ++j)
                v[j] = *(const unsigned int*)(d.msgB + (size_t)s[j] * HD + loff);
            #pragma unroll
            for (int j = 0; j < 8; ++j) {
                bx += b2f(v[j] & 0xffffu);
                by += b2f(v[j] >> 16);
            }
        }
        for (; e < end; ++e) {
            int s0 = d.sortedB[e];
            unsigned int v0 = *(const unsigned int*)(d.msgB + (size_t)s0 * HD + loff);
            bx += b2f(v0 & 0xffffu);
            by += b2f(v0 >> 16);
        }
        float r = d.rsqB[node];
        ox += bx * r; oy += by * r;
    }
    float2 bv = *(const float2*)(d.bias + loff);
    ox = fmaxf(ox + bv.x, 0.f);
    oy = fmaxf(oy + bv.y, 0.f);
    if (OUT_BF16) {
        unsigned int packed = ((unsigned int)f2b(oy) << 16) | f2b(ox);
        ((unsigned int*)d.out)[(size_t)node * (HD / 2) + lane] = packed;
    } else {
        float2 o = {ox, oy};
        ((float2*)d.out)[(size_t)node * (HD / 2) + lane] = o;
    }
}

extern "C" void kernel_launch(void* const* d_in, const int* in_sizes, int n_in,
                              void* d_out, int out_size, void* d_ws, size_t ws_size,
                              hipStream_t stream)
{
    const float* feat[4] = {(const float*)d_in[0], (const float*)d_in[1],
                            (const float*)d_in[2], (const float*)d_in[3]};
    const int* src_all = (const int*)d_in[4];
    const int* dst_all = (const int*)d_in[5];
    const float* Wp  = (const float*)d_in[6];
    const float* bp  = (const float*)d_in[7];
    const float* Wc1 = (const float*)d_in[8];
    const float* bc1 = (const float*)d_in[9];
    const float* Wc2 = (const float*)d_in[10];
    const float* bc2 = (const float*)d_in[11];

    const int N = in_sizes[0] / INF;      // 50000  (< 65536: ushort ids)
    const int E = in_sizes[4] / 5;        // 1,600,000

    // etypes: k -> (src_type, dst_type): (0,1) (1,3) (3,2) (0,2) (2,0)
    const int st_[5] = {0, 1, 3, 0, 2};

    // ---- workspace layout (256B-aligned) ----
    char* w = (char*)d_ws;
    auto take = [&](size_t bytes) { char* p = w; w += (bytes + 255) & ~(size_t)255; return p; };
    int*   cnt_dst = (int*)take(5 * (size_t)N * 4);
    float* rsq_out = (float*)take(5 * (size_t)N * 4);
    float* rsq_in  = (float*)take(5 * (size_t)N * 4);
    int*   off     = (int*)take(5 * (size_t)(N + 1) * 4);
    unsigned short* sorted = (unsigned short*)take(5 * (size_t)E * 2);  // 16 MB, live whole pass
    float* alast   = (float*)take(4 * (size_t)N * 4);
    unsigned short* WpT = (unsigned short*)take(4 * 128 * 384 * 2);
    unsigned short* WcT = (unsigned short*)take(2 * 5 * 128 * 128 * 2);
    float* cbias   = (float*)take(2 * 4 * 128 * 4);

    const size_t pr_bytes = 10u * NWG * (size_t)N * 2 + 5 * (size_t)E * 2;  // partial+rank (32MB)
    const size_t blob_sz = 4 * (size_t)N * 384 * 2;                         // featB (153.6MB)
    size_t fixed_used = (size_t)(w - (char*)d_ws);
    bool roomy = ws_size >= fixed_used + pr_bytes + blob_sz + (1u << 20);

    unsigned short *partial, *rank_local, *featB, *msg;
    if (roomy) {
        // partial/rank in own region; featB in blob; msg overlays featB after proj.
        partial    = (unsigned short*)take(10u * NWG * (size_t)N * 2);
        rank_local = (unsigned short*)take(5 * (size_t)E * 2);
        char* blob = (char*)take(blob_sz);
        featB = (unsigned short*)blob;
        msg   = (unsigned short*)blob;
    } else {
        // overlay (R7 scheme): partial+rank in blob; featB clobbers after permute;
        // msg at blob+32MB clobbers featB after proj.
        char* blob = (char*)take(blob_sz);
        partial    = (unsigned short*)blob;
        rank_local = (unsigned short*)(blob + 10u * NWG * (size_t)N * 2);
        featB      = (unsigned short*)blob;
        msg        = (unsigned short*)(blob + 32u * 1024 * 1024);
    }
    // h0 in d_out lower half (bf16), h1 in d_out upper half (bf16); both dead
    // before layer-2 gathers write f32 over the full d_out.
    unsigned short* h0 = (unsigned short*)d_out;
    unsigned short* h1 = (unsigned short*)d_out + 4 * (size_t)N * HD;

    const int gblk = (N + 63) / 64;

    prep_weights_kernel<<<512, 256, 0, stream>>>(Wp, Wc1, Wc2, bc1, bc2, WpT, WcT, cbias);

    GemmBatch pb = {};
    for (int t = 0; t < 4; ++t) {
        pb.d[t].A = featB + (size_t)t * N * 384;
        pb.d[t].Bt = WpT + (size_t)t * 128 * 384;
        pb.d[t].bias = bp + (size_t)t * HD;
        pb.d[t].rowscale = nullptr;
        pb.d[t].alast = alast + (size_t)t * N;
        pb.d[t].wlast = Wp + (size_t)t * INF * HD + 384 * HD;
        pb.d[t].out = h0 + (size_t)t * N * HD;
    }

    if (roomy) {
        // hist (160 blocks) || convert (512 blocks) in one dispatch
        hist_conv_kernel<<<HIST_BLOCKS + 512, 1024, 0, stream>>>(
            src_all, dst_all, partial, rank_local, E, N,
            feat[0], feat[1], feat[2], feat[3], (unsigned int*)featB, alast);
        reduce_kernel<<<(10 * N + 255) / 256, 256, 0, stream>>>(partial, cnt_dst, rsq_out, rsq_in, N);
        scan_kernel<<<5, 1024, 0, stream>>>(cnt_dst, off, N);
        // proj GEMM (y<4) || permute (y==4) in one dispatch
        permute_proj_kernel<<<dim3(2048, 5), 256, 0, stream>>>(
            pb, 384, N, 384, 1, gblk,
            src_all, dst_all, off, partial, rank_local, sorted, E, N);
    } else {
        hist_conv_kernel<<<HIST_BLOCKS, 1024, 0, stream>>>(
            src_all, dst_all, partial, rank_local, E, N,
            feat[0], feat[1], feat[2], feat[3], (unsigned int*)featB, alast);
        reduce_kernel<<<(10 * N + 255) / 256, 256, 0, stream>>>(partial, cnt_dst, rsq_out, rsq_in, N);
        scan_kernel<<<5, 1024, 0, stream>>>(cnt_dst, off, N);
        permute_kernel<<<2048, 256, 0, stream>>>(src_all, dst_all, off, partial, rank_local,
                                                 sorted, E, N);
        convert_kernel<<<2048, 256, 0, stream>>>(feat[0], feat[1], feat[2], feat[3],
                                                 (unsigned int*)featB, alast, N);
        gemm_mfma_kernel<<<dim3(gblk, 4), 256, 0, stream>>>(pb, 384, N, 384, 1);
    }

    // ---- 2 hetero conv layers ----
    for (int layer = 0; layer < 2; ++layer) {
        const unsigned short* hin = layer ? h1 : h0;
        const unsigned short* WT = WcT + (size_t)layer * 5 * 128 * 128;
        const float* cb = cbias + (size_t)layer * 4 * 128;

        // 5 independent conv GEMMs in one dispatch
        {
            GemmBatch cbch = {};
            for (int k = 0; k < 5; ++k) {
                cbch.d[k].A = hin + (size_t)st_[k] * N * HD;
                cbch.d[k].Bt = WT + (size_t)k * 128 * 128;
                cbch.d[k].bias = nullptr;
                cbch.d[k].rowscale = rsq_out + (size_t)k * N;
                cbch.d[k].alast = nullptr;
                cbch.d[k].wlast = nullptr;
                cbch.d[k].out = msg + (size_t)k * N * HD;
            }
            gemm_mfma_kernel<<<dim3(gblk, 5), 256, 0, stream>>>(cbch, HD, N, 128, 0);
        }

        // 4 gathers (k2+k3 dual into t2) in one dispatch
        {
            auto S = [&](int k) { return sorted + (size_t)k * E; };
            auto O = [&](int k) { return off + (size_t)k * (N + 1); };
            auto R = [&](int k) { return rsq_in + (size_t)k * N; };
            auto M_ = [&](int k) { return msg + (size_t)k * N * HD; };
            const int ksA[4] = {0, 1, 2, 4};
            const int dt [4] = {1, 3, 2, 0};
            GatherBatch gb = {};
            for (int y = 0; y < 4; ++y) {
                int k = ksA[y];
                gb.d[y].msgA = M_(k); gb.d[y].sortedA = S(k);
                gb.d[y].offA = O(k);  gb.d[y].rsqA = R(k);
                gb.d[y].msgB = nullptr; gb.d[y].sortedB = nullptr;
                gb.d[y].offB = nullptr; gb.d[y].rsqB = nullptr;
                gb.d[y].bias = cb + (size_t)dt[y] * HD;
                if (layer == 0)
                    gb.d[y].out = h1 + (size_t)dt[y] * N * HD;
                else
                    gb.d[y].out = (float*)d_out + (size_t)dt[y] * N * HD;
            }
            gb.d[2].msgB = M_(3); gb.d[2].sortedB = S(3);
            gb.d[2].offB = O(3);  gb.d[2].rsqB = R(3);
            const int gg = (N + 3) / 4;
            if (layer == 0)
                gather_kernel<1><<<dim3(gg, 4), 256, 0, stream>>>(gb, N);
            else
                gather_kernel<0><<<dim3(gg, 4), 256, 0, stream>>>(gb, N);
        }
    }
}

// Round 9
// 1119.634 us; speedup vs baseline: 25.8868x; 1.0238x over previous
//
#include <hip/hip_runtime.h>
#include <hip/hip_bf16.h>

#define INF 385
#define HD 128
#define NWG 16   // workgroups per histogram group
#define HIST_BLOCKS (10 * NWG)

typedef __attribute__((ext_vector_type(8))) short short8;
typedef __attribute__((ext_vector_type(4))) float f32x4;

__device__ inline unsigned short f2b(float f) {
    __hip_bfloat16 h = __float2bfloat16(f);
    return *reinterpret_cast<unsigned short*>(&h);
}
__device__ inline float b2f(unsigned int lo16) {
    union { unsigned int u; float f; } c; c.u = lo16 << 16; return c.f;
}

// ---------------- convert body: feat f32 [N][385] -> bf16 [N][384] + alast ----------------
__device__ __forceinline__ void convert_body(
    const float* f0, const float* f1, const float* f2, const float* f3,
    unsigned int* featB, float* alast, int N, int gid, int nthr)
{
    int per = N * 192;
    int tot = 4 * per;
    for (int p = gid; p < tot; p += nthr) {
        int t = p / per, rem = p - t * per;
        int n = rem / 192, c2 = (rem - n * 192) * 2;
        const float* f = (t < 2) ? (t == 0 ? f0 : f1) : (t == 2 ? f2 : f3);
        const float* row = f + (size_t)n * INF;
        float a = row[c2], b = row[c2 + 1];
        featB[p] = ((unsigned int)f2b(b) << 16) | f2b(a);
    }
    for (int p = gid; p < 4 * N; p += nthr) {
        int t = p / N, n = p - t * N;
        const float* f = (t < 2) ? (t == 0 ? f0 : f1) : (t == 2 ? f2 : f3);
        alast[p] = f[(size_t)n * INF + 384];
    }
}

// ---------------- fused: LDS-privatized histogram (blocks<HIST_BLOCKS) + convert ----------------
__global__ __launch_bounds__(1024) void hist_conv_kernel(
    const int* __restrict__ src_all, const int* __restrict__ dst_all,
    unsigned short* __restrict__ partial,    // [10][NWG][N]
    unsigned short* __restrict__ rank_local, // [5][E]
    int E, int N,
    const float* __restrict__ f0, const float* __restrict__ f1,
    const float* __restrict__ f2, const float* __restrict__ f3,
    unsigned int* __restrict__ featB, float* __restrict__ alast)
{
    __shared__ unsigned int cnt[25000];      // 2 packed ushort counters per uint
    int tid = threadIdx.x;
    if (blockIdx.x >= HIST_BLOCKS) {
        int nconv = gridDim.x - HIST_BLOCKS;
        convert_body(f0, f1, f2, f3, featB, alast, N,
                     (blockIdx.x - HIST_BLOCKS) * 1024 + tid, nconv * 1024);
        return;
    }
    int g = blockIdx.x / NWG;
    int w = blockIdx.x % NWG;
    int half = (N + 1) / 2;
    for (int i = tid; i < half; i += 1024) cnt[i] = 0;
    __syncthreads();

    int C = (E + NWG - 1) / NWG;
    int lo = w * C, hi = min(lo + C, E);
    if (g < 5) {
        const int* arr = dst_all + (size_t)g * E;
        for (int e = lo + tid; e < hi; e += 1024) {
            int d = __builtin_nontemporal_load(&arr[e]);
            unsigned int sh = (d & 1) * 16;
            unsigned int old = atomicAdd(&cnt[d >> 1], 1u << sh);
            rank_local[(size_t)g * E + e] = (unsigned short)((old >> sh) & 0xffffu);
        }
    } else {
        const int* arr = src_all + (size_t)(g - 5) * E;
        for (int e = lo + tid; e < hi; e += 1024) {
            int d = __builtin_nontemporal_load(&arr[e]);
            atomicAdd(&cnt[d >> 1], 1u << ((d & 1) * 16));
        }
    }
    __syncthreads();
    unsigned short* outp = partial + ((size_t)g * NWG + w) * N;
    for (int n = tid; n < N; n += 1024)
        outp[n] = (unsigned short)((cnt[n >> 1] >> ((n & 1) * 16)) & 0xffffu);
}

// ---------------- reduce partials -> degrees/rsqrt; in-place exclusive prefix over chunks ----------------
__global__ void reduce_kernel(unsigned short* __restrict__ partial, int* __restrict__ cnt_dst,
                              float* __restrict__ rsq_out, float* __restrict__ rsq_in, int N) {
    int i = blockIdx.x * blockDim.x + threadIdx.x;
    int stride = gridDim.x * blockDim.x;
    int tot = 10 * N;
    for (; i < tot; i += stride) {
        int g = i / N, n = i - g * N;
        unsigned short* p = partial + ((size_t)g * NWG) * N + n;
        int sum = 0;
        #pragma unroll
        for (int w = 0; w < NWG; ++w) {
            int v = p[(size_t)w * N];
            p[(size_t)w * N] = (unsigned short)sum;   // exclusive prefix (rank base per chunk)
            sum += v;
        }
        float r = rsqrtf((float)max(sum, 1));
        if (g < 5) { cnt_dst[i] = sum; rsq_in[i] = r; }
        else rsq_out[i - 5 * N] = r;
    }
}

// 5 blocks, one per etype
__global__ __launch_bounds__(1024) void scan_kernel(const int* __restrict__ cnt_all,
                                                    int* __restrict__ off_all, int n) {
    const int* cnt = cnt_all + (size_t)blockIdx.x * n;
    int* off = off_all + (size_t)blockIdx.x * (n + 1);
    __shared__ int ssum[1024];
    int t = threadIdx.x;
    int chunk = (n + 1023) / 1024;
    int lo = t * chunk, hi = min(lo + chunk, n);
    int s = 0;
    for (int i = lo; i < hi; ++i) s += cnt[i];
    ssum[t] = s;
    __syncthreads();
    for (int d = 1; d < 1024; d <<= 1) {
        int v = (t >= d) ? ssum[t - d] : 0;
        __syncthreads();
        ssum[t] += v;
        __syncthreads();
    }
    int excl = (t == 0) ? 0 : ssum[t - 1];
    for (int i = lo; i < hi; ++i) { off[i] = excl; excl += cnt[i]; }
    if (t == 1023) off[n] = ssum[1023];
}

// ---------------- atomic-free permutation: sorted_src (ushort) grouped by dst ----------------
__global__ void permute_kernel(const int* __restrict__ src_all, const int* __restrict__ dst_all,
                               const int* __restrict__ off, const unsigned short* __restrict__ partial,
                               const unsigned short* __restrict__ rank_local,
                               unsigned short* __restrict__ sorted, int E, int N) {
    int i = blockIdx.x * blockDim.x + threadIdx.x;
    int nthr = gridDim.x * blockDim.x;
    int tot = 5 * E;
    int C = (E + NWG - 1) / NWG;
    for (; i < tot; i += nthr) {
        int k = i / E, e = i - k * E;
        int w = e / C;
        int d = __builtin_nontemporal_load(&dst_all[i]);
        int s = __builtin_nontemporal_load(&src_all[i]);
        int rl = __builtin_nontemporal_load(&rank_local[i]);
        int pos = off[(size_t)k * (N + 1) + d]
                + partial[((size_t)k * NWG + w) * N + d]
                + rl;
        __builtin_nontemporal_store((unsigned short)s, &sorted[(size_t)k * E + pos]);
    }
}

// ---------------- feat convert (standalone, fallback path) ----------------
__global__ void convert_kernel(const float* __restrict__ f0, const float* __restrict__ f1,
                               const float* __restrict__ f2, const float* __restrict__ f3,
                               unsigned int* __restrict__ featB, float* __restrict__ alast, int N) {
    convert_body(f0, f1, f2, f3, featB, alast, N,
                 blockIdx.x * blockDim.x + threadIdx.x, gridDim.x * blockDim.x);
}

// ---------------- weight prep: transpose + bf16, combined biases ----------------
__global__ void prep_weights_kernel(const float* __restrict__ Wp,
                                    const float* __restrict__ Wc1, const float* __restrict__ Wc2,
                                    const float* __restrict__ bc1, const float* __restrict__ bc2,
                                    unsigned short* __restrict__ WpT,
                                    unsigned short* __restrict__ WcT,
                                    float* __restrict__ cbias) {
    int i = blockIdx.x * blockDim.x + threadIdx.x;
    int stride = gridDim.x * blockDim.x;
    const int nWp = 4 * 128 * 384;
    for (int p = i; p < nWp; p += stride) {
        int t = p / (128 * 384), rem = p % (128 * 384);
        int c = rem / 384, k = rem % 384;
        WpT[p] = f2b(Wp[(size_t)t * INF * HD + (size_t)k * HD + c]);
    }
    const int nWc = 5 * 128 * 128;
    for (int p = i; p < 2 * nWc; p += stride) {
        int layer = p / nWc, rem = p % nWc;
        int e = rem / (128 * 128), rem2 = rem % (128 * 128);
        int c = rem2 / 128, k = rem2 % 128;
        const float* W = layer ? Wc2 : Wc1;
        WcT[p] = f2b(W[(size_t)e * 128 * 128 + (size_t)k * 128 + c]);
    }
    // cbias[layer][t][c]: t0<-bc[4], t1<-bc[0], t2<-bc[2]+bc[3], t3<-bc[1]
    for (int p = i; p < 2 * 4 * 128; p += stride) {
        int layer = p / 512, rem = p % 512;
        int t = rem / 128, c = rem % 128;
        const float* bc = layer ? bc2 : bc1;
        float v;
        if (t == 0) v = bc[4 * 128 + c];
        else if (t == 1) v = bc[0 * 128 + c];
        else if (t == 2) v = bc[2 * 128 + c] + bc[3 * 128 + c];
        else v = bc[1 * 128 + c];
        cbias[p] = v;
    }
}

// ---------------- batched MFMA GEMM (bf16 A), optional rank-1 / bias / rowscale ----------------
struct GemmDesc {
    const unsigned short* A;      // [M][lda] bf16, rows 16B-aligned
    const unsigned short* Bt;     // [128][K] bf16
    const float* bias;            // [128] or null
    const float* rowscale;        // [M] or null
    const float* alast;           // [M] or null (rank-1 left vector)
    const float* wlast;           // [128] or null (rank-1 right vector)
    unsigned short* out;          // [M][128] bf16
};
struct GemmBatch { GemmDesc d[5]; };

__global__ __launch_bounds__(256) void gemm_mfma_kernel(
    GemmBatch batch, int lda, int M, int K, int relu)
{
    const GemmDesc dsc = batch.d[blockIdx.y];
    const unsigned short* __restrict__ Bt = dsc.Bt;
    const unsigned short* __restrict__ A = dsc.A;

    __shared__ __align__(16) unsigned short As[64][72];   // +8 pad: 144B row stride
    __shared__ __align__(16) unsigned short Bs[128][72];
    const int tid = threadIdx.x;
    const int bm = blockIdx.x * 64;
    const int wid = tid >> 6, lane = tid & 63;
    const int wr = wid & 1, wc = wid >> 1;      // 2x2 wave grid: 32 rows x 64 cols each
    const int l15 = lane & 15, l4 = lane >> 4;

    f32x4 acc[2][4] = {};

    for (int k0 = 0; k0 < K; k0 += 64) {
        {
            int r = tid >> 2, q = tid & 3;      // 16 bf16 per thread, vectorized
            int gm = bm + r;
            if (gm < M) {
                const uint4* g = (const uint4*)(A + (size_t)gm * lda + k0 + q * 16);
                *(uint4*)&As[r][q * 16] = g[0];
                *(uint4*)&As[r][q * 16 + 8] = g[1];
            } else {
                uint4 z = {0, 0, 0, 0};
                *(uint4*)&As[r][q * 16] = z;
                *(uint4*)&As[r][q * 16 + 8] = z;
            }
        }
        {
            int col = tid >> 1, hf = tid & 1;   // 32 bf16 per thread from Bt[col][k0+hf*32..]
            const uint4* g = (const uint4*)(Bt + (size_t)col * K + k0 + hf * 32);
            #pragma unroll
            for (int j = 0; j < 4; ++j)
                *(uint4*)&Bs[col][hf * 32 + j * 8] = g[j];
        }
        __syncthreads();
        #pragma unroll
        for (int kk = 0; kk < 2; ++kk) {
            short8 a[2], b[4];
            #pragma unroll
            for (int mi = 0; mi < 2; ++mi)
                a[mi] = *(const short8*)&As[wr * 32 + mi * 16 + l15][kk * 32 + l4 * 8];
            #pragma unroll
            for (int ni = 0; ni < 4; ++ni)
                b[ni] = *(const short8*)&Bs[wc * 64 + ni * 16 + l15][kk * 32 + l4 * 8];
            #pragma unroll
            for (int mi = 0; mi < 2; ++mi)
                #pragma unroll
                for (int ni = 0; ni < 4; ++ni)
                    acc[mi][ni] = __builtin_amdgcn_mfma_f32_16x16x32_bf16(
                        a[mi], b[ni], acc[mi][ni], 0, 0, 0);
        }
        __syncthreads();
    }

    // epilogue: C/D layout col=lane&15, row=(lane>>4)*4+reg  [m89-verified]
    #pragma unroll
    for (int mi = 0; mi < 2; ++mi) {
        #pragma unroll
        for (int r = 0; r < 4; ++r) {
            int grow = bm + wr * 32 + mi * 16 + l4 * 4 + r;
            if (grow >= M) continue;
            float rs = dsc.rowscale ? dsc.rowscale[grow] : 1.f;
            float al = dsc.alast ? dsc.alast[grow] : 0.f;
            #pragma unroll
            for (int ni = 0; ni < 4; ++ni) {
                int gcol = wc * 64 + ni * 16 + l15;
                float v = acc[mi][ni][r];
                if (dsc.wlast) v += al * dsc.wlast[gcol];
                if (dsc.bias) v += dsc.bias[gcol];
                v *= rs;
                if (relu) v = fmaxf(v, 0.f);
                dsc.out[(size_t)grow * HD + gcol] = f2b(v);
            }
        }
    }
}

// ---------------- batched CSR gather: one wave per node, 16-edge unroll, fused bias+relu ----------------
struct GatherDesc {
    const unsigned short* msgA; const unsigned short* sortedA;
    const int* offA; const float* rsqA;
    const unsigned short* msgB; const unsigned short* sortedB;  // null if single
    const int* offB; const float* rsqB;
    const float* bias; void* out;
};
struct GatherBatch { GatherDesc d[4]; };

__device__ __forceinline__ void gather_seg(
    const unsigned short* __restrict__ msg, const unsigned short* __restrict__ sorted,
    int beg, int end, size_t loff, float& ax, float& ay)
{
    int e = beg;
    for (; e + 16 <= end; e += 16) {
        int s[16];
        unsigned int v[16];
        #pragma unroll
        for (int j = 0; j < 16; ++j) s[j] = sorted[e + j];
        #pragma unroll
        for (int j = 0; j < 16; ++j)
            v[j] = *(const unsigned int*)(msg + (size_t)s[j] * HD + loff);
        #pragma unroll
        for (int j = 0; j < 16; ++j) {
            ax += b2f(v[j] & 0xffffu);
            ay += b2f(v[j] >> 16);
        }
    }
    if (e + 8 <= end) {
        int s[8];
        unsigned int v[8];
        #pragma unroll
        for (int j = 0; j < 8; ++j) s[j] = sorted[e + j];
        #pragma unroll
        for (int j = 0; j < 8; ++j)
            v[j] = *(const unsigned int*)(msg + (size_t)s[j] * HD + loff);
        #pragma unroll
        for (int j = 0; j < 8; ++j) {
            ax += b2f(v[j] & 0xffffu);
            ay += b2f(v[j] >> 16);
        }
        e += 8;
    }
    for (; e < end; ++e) {
        int s0 = sorted[e];
        unsigned int v0 = *(const unsigned int*)(msg + (size_t)s0 * HD + loff);
        ax += b2f(v0 & 0xffffu);
        ay += b2f(v0 >> 16);
    }
}

template<int OUT_BF16>
__global__ __launch_bounds__(256) void gather_kernel(GatherBatch batch, int n)
{
    const GatherDesc d = batch.d[blockIdx.y];
    int node = blockIdx.x * 4 + (threadIdx.x >> 6);
    if (node >= n) return;
    int lane = threadIdx.x & 63;
    const size_t loff = (size_t)lane * 2;

    float ox, oy;
    {
        float ax = 0.f, ay = 0.f;
        gather_seg(d.msgA, d.sortedA, d.offA[node], d.offA[node + 1], loff, ax, ay);
        float r = d.rsqA[node];
        ox = ax * r; oy = ay * r;
    }
    if (d.msgB) {
        float bx = 0.f, by = 0.f;
        gather_seg(d.msgB, d.sortedB, d.offB[node], d.offB[node + 1], loff, bx, by);
        float r = d.rsqB[node];
        ox += bx * r; oy += by * r;
    }
    float2 bv = *(const float2*)(d.bias + loff);
    ox = fmaxf(ox + bv.x, 0.f);
    oy = fmaxf(oy + bv.y, 0.f);
    if (OUT_BF16) {
        unsigned int packed = ((unsigned int)f2b(oy) << 16) | f2b(ox);
        ((unsigned int*)d.out)[(size_t)node * (HD / 2) + lane] = packed;
    } else {
        float2 o = {ox, oy};
        ((float2*)d.out)[(size_t)node * (HD / 2) + lane] = o;
    }
}

extern "C" void kernel_launch(void* const* d_in, const int* in_sizes, int n_in,
                              void* d_out, int out_size, void* d_ws, size_t ws_size,
                              hipStream_t stream)
{
    const float* feat[4] = {(const float*)d_in[0], (const float*)d_in[1],
                            (const float*)d_in[2], (const float*)d_in[3]};
    const int* src_all = (const int*)d_in[4];
    const int* dst_all = (const int*)d_in[5];
    const float* Wp  = (const float*)d_in[6];
    const float* bp  = (const float*)d_in[7];
    const float* Wc1 = (const float*)d_in[8];
    const float* bc1 = (const float*)d_in[9];
    const float* Wc2 = (const float*)d_in[10];
    const float* bc2 = (const float*)d_in[11];

    const int N = in_sizes[0] / INF;      // 50000  (< 65536: ushort ids)
    const int E = in_sizes[4] / 5;        // 1,600,000

    // etypes: k -> (src_type, dst_type): (0,1) (1,3) (3,2) (0,2) (2,0)
    const int st_[5] = {0, 1, 3, 0, 2};

    // ---- workspace layout (256B-aligned) ----
    char* w = (char*)d_ws;
    auto take = [&](size_t bytes) { char* p = w; w += (bytes + 255) & ~(size_t)255; return p; };
    int*   cnt_dst = (int*)take(5 * (size_t)N * 4);
    float* rsq_out = (float*)take(5 * (size_t)N * 4);
    float* rsq_in  = (float*)take(5 * (size_t)N * 4);
    int*   off     = (int*)take(5 * (size_t)(N + 1) * 4);
    unsigned short* sorted = (unsigned short*)take(5 * (size_t)E * 2);  // 16 MB, live whole pass
    float* alast   = (float*)take(4 * (size_t)N * 4);
    unsigned short* WpT = (unsigned short*)take(4 * 128 * 384 * 2);
    unsigned short* WcT = (unsigned short*)take(2 * 5 * 128 * 128 * 2);
    float* cbias   = (float*)take(2 * 4 * 128 * 4);

    const size_t pr_bytes = 10u * NWG * (size_t)N * 2 + 5 * (size_t)E * 2;  // partial+rank (32MB)
    const size_t blob_sz = 4 * (size_t)N * 384 * 2;                         // featB (153.6MB)
    size_t fixed_used = (size_t)(w - (char*)d_ws);
    bool roomy = ws_size >= fixed_used + pr_bytes + blob_sz + (1u << 20);

    unsigned short *partial, *rank_local, *featB, *msg;
    if (roomy) {
        partial    = (unsigned short*)take(10u * NWG * (size_t)N * 2);
        rank_local = (unsigned short*)take(5 * (size_t)E * 2);
        char* blob = (char*)take(blob_sz);
        featB = (unsigned short*)blob;
        msg   = (unsigned short*)blob;   // overlays featB after proj
    } else {
        char* blob = (char*)take(blob_sz);
        partial    = (unsigned short*)blob;
        rank_local = (unsigned short*)(blob + 10u * NWG * (size_t)N * 2);
        featB      = (unsigned short*)blob;
        msg        = (unsigned short*)(blob + 32u * 1024 * 1024);
    }
    // h0 in d_out lower half (bf16), h1 in d_out upper half (bf16); both dead
    // before layer-2 gathers write f32 over the full d_out.
    unsigned short* h0 = (unsigned short*)d_out;
    unsigned short* h1 = (unsigned short*)d_out + 4 * (size_t)N * HD;

    const int gblk = (N + 63) / 64;

    prep_weights_kernel<<<512, 256, 0, stream>>>(Wp, Wc1, Wc2, bc1, bc2, WpT, WcT, cbias);

    // hist (160 blocks) || convert (512 blocks if roomy) in one dispatch
    hist_conv_kernel<<<roomy ? HIST_BLOCKS + 512 : HIST_BLOCKS, 1024, 0, stream>>>(
        src_all, dst_all, partial, rank_local, E, N,
        feat[0], feat[1], feat[2], feat[3], (unsigned int*)featB, alast);
    reduce_kernel<<<(10 * N + 255) / 256, 256, 0, stream>>>(partial, cnt_dst, rsq_out, rsq_in, N);
    scan_kernel<<<5, 1024, 0, stream>>>(cnt_dst, off, N);
    permute_kernel<<<2048, 256, 0, stream>>>(src_all, dst_all, off, partial, rank_local,
                                             sorted, E, N);
    if (!roomy)
        convert_kernel<<<2048, 256, 0, stream>>>(feat[0], feat[1], feat[2], feat[3],
                                                 (unsigned int*)featB, alast, N);

    // ---- input projections (batched over 4 types) ----
    {
        GemmBatch pb = {};
        for (int t = 0; t < 4; ++t) {
            pb.d[t].A = featB + (size_t)t * N * 384;
            pb.d[t].Bt = WpT + (size_t)t * 128 * 384;
            pb.d[t].bias = bp + (size_t)t * HD;
            pb.d[t].rowscale = nullptr;
            pb.d[t].alast = alast + (size_t)t * N;
            pb.d[t].wlast = Wp + (size_t)t * INF * HD + 384 * HD;
            pb.d[t].out = h0 + (size_t)t * N * HD;
        }
        gemm_mfma_kernel<<<dim3(gblk, 4), 256, 0, stream>>>(pb, 384, N, 384, 1);
    }

    // ---- 2 hetero conv layers ----
    for (int layer = 0; layer < 2; ++layer) {
        const unsigned short* hin = layer ? h1 : h0;
        const unsigned short* WT = WcT + (size_t)layer * 5 * 128 * 128;
        const float* cb = cbias + (size_t)layer * 4 * 128;

        // 5 independent conv GEMMs in one dispatch
        {
            GemmBatch cbch = {};
            for (int k = 0; k < 5; ++k) {
                cbch.d[k].A = hin + (size_t)st_[k] * N * HD;
                cbch.d[k].Bt = WT + (size_t)k * 128 * 128;
                cbch.d[k].bias = nullptr;
                cbch.d[k].rowscale = rsq_out + (size_t)k * N;
                cbch.d[k].alast = nullptr;
                cbch.d[k].wlast = nullptr;
                cbch.d[k].out = msg + (size_t)k * N * HD;
            }
            gemm_mfma_kernel<<<dim3(gblk, 5), 256, 0, stream>>>(cbch, HD, N, 128, 0);
        }

        // 4 gathers (k2+k3 dual into t2) in one dispatch
        {
            auto S = [&](int k) { return sorted + (size_t)k * E; };
            auto O = [&](int k) { return off + (size_t)k * (N + 1); };
            auto R = [&](int k) { return rsq_in + (size_t)k * N; };
            auto M_ = [&](int k) { return msg + (size_t)k * N * HD; };
            const int ksA[4] = {0, 1, 2, 4};
            const int dt [4] = {1, 3, 2, 0};
            GatherBatch gb = {};
            for (int y = 0; y < 4; ++y) {
                int k = ksA[y];
                gb.d[y].msgA = M_(k); gb.d[y].sortedA = S(k);
                gb.d[y].offA = O(k);  gb.d[y].rsqA = R(k);
                gb.d[y].msgB = nullptr; gb.d[y].sortedB = nullptr;
                gb.d[y].offB = nullptr; gb.d[y].rsqB = nullptr;
                gb.d[y].bias = cb + (size_t)dt[y] * HD;
                if (layer == 0)
                    gb.d[y].out = h1 + (size_t)dt[y] * N * HD;
                else
                    gb.d[y].out = (float*)d_out + (size_t)dt[y] * N * HD;
            }
            gb.d[2].msgB = M_(3); gb.d[2].sortedB = S(3);
            gb.d[2].offB = O(3);  gb.d[2].rsqB = R(3);
            const int gg = (N + 3) / 4;
            if (layer == 0)
                gather_kernel<1><<<dim3(gg, 4), 256, 0, stream>>>(gb, N);
            else
                gather_kernel<0><<<dim3(gg, 4), 256, 0, stream>>>(gb, N);
        }
    }
}